// Round 4
// baseline (306.492 us; speedup 1.0000x reference)
//
#include <hip/hip_runtime.h>

#define D 256
#define VOCAB 4096
#define NTOT 16384      // 16 * 32 * 32
#define N_OUT0 4194304  // 16*256*32*32

typedef _Float16 half8 __attribute__((ext_vector_type(8)));
typedef float f32x4 __attribute__((ext_vector_type(4)));
typedef unsigned long long u64;

__device__ __forceinline__ void gld16(const void* g, void* l) {
    __builtin_amdgcn_global_load_lds(
        (const __attribute__((address_space(1))) void*)g,
        (__attribute__((address_space(3))) void*)l, 16, 0, 0);
}

__device__ __forceinline__ u64 pack_key(float d, int v) {
    unsigned u = __float_as_uint(d);
    u ^= ((unsigned)((int)u >> 31)) | 0x80000000u;  // monotonic float->uint
    return ((u64)u << 32) | (unsigned)v;
}

__device__ __forceinline__ float unpack_dist(u64 k) {
    unsigned u = (unsigned)(k >> 32);
    u = (u & 0x80000000u) ? (u ^ 0x80000000u) : ~u;
    return __uint_as_float(u);
}

// ---------------- prep: esq + per-block e2max partials + out2 zero ----------------
__global__ __launch_bounds__(256) void k_prep(const float* __restrict__ emb,
                                              float* __restrict__ esq,
                                              float* __restrict__ e2maxp,
                                              float* __restrict__ out2) {
    __shared__ float sm[4];
    const int tid = threadIdx.x, lane = tid & 63, wv = tid >> 6;
    const int v0 = blockIdx.x * 64;
    float lmax = 0.0f;
#pragma unroll 4
    for (int i = 0; i < 16; ++i) {
        int v = v0 + i * 4 + wv;
        float4 e = *(const float4*)(emb + (size_t)v * D + lane * 4);
        float s = e.x * e.x + e.y * e.y + e.z * e.z + e.w * e.w;
#pragma unroll
        for (int m = 32; m >= 1; m >>= 1) s += __shfl_xor(s, m, 64);
        if (lane == 0) esq[v] = s;
        lmax = fmaxf(lmax, s);
    }
    if (lane == 0) sm[wv] = lmax;
    __syncthreads();
    if (tid == 0) {
        e2maxp[blockIdx.x] = fmaxf(fmaxf(sm[0], sm[1]), fmaxf(sm[2], sm[3]));
        if (blockIdx.x == 0) out2[0] = 0.0f;
    }
}

// ---------------- fused pack (hi-only) + hsq partials + E2max reduce ----------------
// blocks 0..511: pack A (hi) + hsq partials; 512..767: pack B (hi); 768: E2max
// Apk (halfs): [bm 64][w 8][q 4][r 256][j 8]   window = 8192 halfs
// Bpk (halfs): [bn 32][w 8][q 4][r 128][j 8]   window = 4096 halfs
__global__ __launch_bounds__(256) void k_pack(const float* __restrict__ h,
                                              const float* __restrict__ emb,
                                              _Float16* __restrict__ Apk,
                                              _Float16* __restrict__ Bpk,
                                              float* __restrict__ hsqp,
                                              const float* __restrict__ e2maxp,
                                              float* __restrict__ E2max) {
    __shared__ float S[8192];
    const int tid = threadIdx.x;
    const int bid = blockIdx.x;
    if (bid < 512) {
        const int bm = bid >> 3, w = bid & 7;
        const int b = bm >> 2, p0 = (bm & 3) * 256;
        const float* src = h + ((size_t)b << 18) + p0;
#pragma unroll 4
        for (int cl = 0; cl < 32; ++cl)
            S[cl * 256 + tid] = src[(size_t)(w * 32 + cl) << 10 | (unsigned)tid];
        __syncthreads();
        // hsq partial for this 32-channel slice, row = tid (exact f32 h values)
        float sq = 0.0f;
#pragma unroll
        for (int cl = 0; cl < 32; ++cl) {
            float t = S[cl * 256 + tid];
            sq = fmaf(t, t, sq);
        }
        hsqp[(size_t)(bm * 8 + w) * 256 + tid] = sq;
        _Float16* dstT = Apk + (size_t)bm * 65536 + (size_t)w * 8192;
#pragma unroll
        for (int i = 0; i < 4; ++i) {  // q = i, r = tid
            alignas(16) _Float16 hi[8];
#pragma unroll
            for (int j = 0; j < 8; ++j) hi[j] = (_Float16)S[(i * 8 + j) * 256 + tid];
            *(half8*)(dstT + i * 2048 + tid * 8) = *(half8*)hi;
        }
    } else if (bid < 768) {
        const int bid2 = bid - 512;
        const int bn = bid2 >> 3, w = bid2 & 7;
        const int v0 = bn * 128;
#pragma unroll 4
        for (int i = 0; i < 16; ++i) {
            int flat = i * 256 + tid;
            int r = flat >> 5, cl = flat & 31;
            S[cl * 129 + r] = emb[(size_t)(v0 + r) * D + w * 32 + cl];
        }
        __syncthreads();
        _Float16* dstT = Bpk + (size_t)bn * 32768 + (size_t)w * 4096;
#pragma unroll
        for (int i = 0; i < 2; ++i) {
            int s = i * 256 + tid;
            int q = s >> 7, r = s & 127;
            alignas(16) _Float16 hi[8];
#pragma unroll
            for (int j = 0; j < 8; ++j) hi[j] = (_Float16)S[(q * 8 + j) * 129 + r];
            *(half8*)(dstT + q * 1024 + r * 8) = *(half8*)hi;
        }
    } else {
        // E2max = max over 64 per-block partials (runs after k_prep: separate launch)
        if (tid < 64) {
            float m = e2maxp[tid];
#pragma unroll
            for (int s = 32; s >= 1; s >>= 1) m = fmaxf(m, __shfl_xor(m, s, 64));
            if (tid == 0) E2max[0] = m;
        }
    }
}

// ---------------- distance GEMM (single fp16 pass) + per-(row,bn) top-2 ----------------
// Tile 128m x 128n, 256 threads = 4 waves (2m x 2n), wave tile 64x64 = 4x4 frags.
// Triple-buffered LDS (As/Bs 3x8KB = 48KB -> 3 blocks/CU), counted vmcnt(4),
// raw barrier per window (R1-verified PHASE_END pattern). 8 windows of K=32.
// Epilogue: per (row, bn) TOP-2 keys -> keys2[bn][row][2]. Approximate distances:
// refine in k_gather recovers the exact argmin via a sound error window.

#define STAGE(W, BUF) do { \
    _Pragma("unroll") \
    for (int s_ = 0; s_ < 2; ++s_) { \
        int f_ = s_ * 256 + tid; \
        gld16(AgH + (W) * 8192 + (f_ >> 7) * 2048 + (f_ & 127) * 8, \
              As + (BUF) * 4096 + f_ * 8); \
    } \
    _Pragma("unroll") \
    for (int s_ = 0; s_ < 2; ++s_) { \
        int f_ = s_ * 256 + tid; \
        gld16(Bg + (W) * 4096 + f_ * 8, Bs + (BUF) * 4096 + f_ * 8); \
    } } while (0)

#define PHASE_END(N) do { \
    __builtin_amdgcn_sched_barrier(0); \
    asm volatile("s_waitcnt vmcnt(" #N ")" ::: "memory"); \
    __builtin_amdgcn_s_barrier(); } while (0)

#define WINDOW(BUF, DOSTAGE, SW, SBUF) do { \
    const _Float16* aB = As + (BUF) * 4096 + quad * 1024 + (wm * 64 + j16) * 8; \
    const _Float16* bB = Bs + (BUF) * 4096 + quad * 1024 + (wn * 64 + j16) * 8; \
    if (DOSTAGE) STAGE(SW, SBUF); \
    half8 af[4], bf[4]; \
    _Pragma("unroll") \
    for (int mt_ = 0; mt_ < 4; ++mt_) af[mt_] = *(const half8*)(aB + mt_ * 128); \
    _Pragma("unroll") \
    for (int nt_ = 0; nt_ < 4; ++nt_) bf[nt_] = *(const half8*)(bB + nt_ * 128); \
    __builtin_amdgcn_s_setprio(1); \
    _Pragma("unroll") \
    for (int mt_ = 0; mt_ < 4; ++mt_) { \
      _Pragma("unroll") \
      for (int nt_ = 0; nt_ < 4; ++nt_) \
        acc[mt_][nt_] = __builtin_amdgcn_mfma_f32_16x16x32_f16(af[mt_], bf[nt_], acc[mt_][nt_], 0, 0, 0); \
    } \
    __builtin_amdgcn_s_setprio(0); \
  } while (0)

__global__ __launch_bounds__(256, 3) void k_gemm(const _Float16* __restrict__ Apk,
                                                 const _Float16* __restrict__ Bpk,
                                                 const float* __restrict__ esq,
                                                 u64* __restrict__ keys2) {
    __shared__ alignas(16) _Float16 As[12288];  // 3 x [q 4][r 128][j 8] = 24KB
    __shared__ alignas(16) _Float16 Bs[12288];  // 3 x [q 4][r 128][j 8] = 24KB

    const int tid = threadIdx.x;
    const int bid = blockIdx.x;
    // XCD-chunked bijective swizzle (4096 % 8 == 0); bn fastest for A-panel L2 reuse
    const int swz = (bid & 7) * 512 + (bid >> 3);
    const int bm = swz >> 5, bn = swz & 31;
    const int m0 = bm * 128, n0 = bn * 128;

    // Apk panels are 256 rows: this block takes half (bm&1) of panel bm>>1
    const _Float16* AgH = Apk + (size_t)(bm >> 1) * 65536 + (size_t)(bm & 1) * 1024;
    const _Float16* Bg = Bpk + (size_t)bn * 32768;

    STAGE(0, 0);
    STAGE(1, 1);

    const int wv = tid >> 6, l = tid & 63;
    const int wm = wv & 1, wn = wv >> 1;
    const int quad = l >> 4, j16 = l & 15;

    f32x4 acc[4][4];
#pragma unroll
    for (int i = 0; i < 4; ++i)
#pragma unroll
        for (int j = 0; j < 4; ++j) acc[i][j] = (f32x4)0.0f;

    asm volatile("s_waitcnt vmcnt(4)" ::: "memory");  // window 0 landed; w1 in flight
    __builtin_amdgcn_s_barrier();

    WINDOW(0, 1, 2, 2); PHASE_END(4);   // w0; stage w2; wait: w1 ready
    WINDOW(1, 1, 3, 0); PHASE_END(4);   // w1; stage w3; wait: w2 ready
    WINDOW(2, 1, 4, 1); PHASE_END(4);
    WINDOW(0, 1, 5, 2); PHASE_END(4);
    WINDOW(1, 1, 6, 0); PHASE_END(4);
    WINDOW(2, 1, 7, 1); PHASE_END(4);
    WINDOW(0, 0, 0, 0); PHASE_END(0);   // w6; wait: w7 ready
    WINDOW(1, 0, 0, 0);                 // w7
    __syncthreads();                    // all MFMA reads done; As reusable

    // epilogue: per-(row, bn) top-2 of approx dist keys
    u64* t2 = (u64*)As;  // [128][wn 2][2] = 4KB, aliases dead As
    float es[4];
    int vidx[4];
#pragma unroll
    for (int nt = 0; nt < 4; ++nt) {
        vidx[nt] = n0 + wn * 64 + nt * 16 + j16;
        es[nt] = esq[vidx[nt]];
    }
#pragma unroll
    for (int mt = 0; mt < 4; ++mt) {
#pragma unroll
        for (int r = 0; r < 4; ++r) {
            u64 m1 = ~0ULL, m2 = ~0ULL;
#pragma unroll
            for (int nt = 0; nt < 4; ++nt) {
                float dv = es[nt] - 2.0f * acc[mt][nt][r];
                u64 k = pack_key(dv, vidx[nt]);
                if (k < m1) { m2 = m1; m1 = k; }
                else if (k < m2) { m2 = k; }
            }
#pragma unroll
            for (int m = 8; m >= 1; m >>= 1) {
                u64 o1 = __shfl_xor(m1, m, 64), o2 = __shfl_xor(m2, m, 64);
                u64 hi = m1 > o1 ? m1 : o1;
                m1 = m1 < o1 ? m1 : o1;
                u64 lo2 = m2 < o2 ? m2 : o2;
                m2 = hi < lo2 ? hi : lo2;
            }
            if (j16 == 0) {
                int row = wm * 64 + mt * 16 + quad * 4 + r;
                t2[row * 4 + wn * 2 + 0] = m1;
                t2[row * 4 + wn * 2 + 1] = m2;
            }
        }
    }
    __syncthreads();
    if (tid < 128) {
        u64 a1 = t2[tid * 4 + 0], a2 = t2[tid * 4 + 1];
        u64 b1 = t2[tid * 4 + 2], b2 = t2[tid * 4 + 3];
        u64 M1 = a1 < b1 ? a1 : b1;
        u64 x = a1 < b1 ? b1 : a1;
        u64 y = a2 < b2 ? a2 : b2;
        u64 M2 = x < y ? x : y;
        keys2[(size_t)bn * (NTOT * 2) + (size_t)(m0 + tid) * 2 + 0] = M1;
        keys2[(size_t)bn * (NTOT * 2) + (size_t)(m0 + tid) * 2 + 1] = M2;
    }
}

// ---------------- refine (windowed exact argmin) + gather + outputs + loss ----------------
__device__ __forceinline__ u64 exact_key(const float* __restrict__ h,
                                         const float* __restrict__ emb,
                                         const float* __restrict__ esq,
                                         int rg, int v, int lane) {
    const float* hb = h + (((size_t)(rg >> 10)) << 18) + (rg & 1023);
    const float4 e4 = *(const float4*)(emb + (size_t)v * D + lane * 4);
    float p = 0.0f;
    p = fmaf(hb[(size_t)(lane * 4 + 0) << 10], e4.x, p);
    p = fmaf(hb[(size_t)(lane * 4 + 1) << 10], e4.y, p);
    p = fmaf(hb[(size_t)(lane * 4 + 2) << 10], e4.z, p);
    p = fmaf(hb[(size_t)(lane * 4 + 3) << 10], e4.w, p);
#pragma unroll
    for (int m = 32; m >= 1; m >>= 1) p += __shfl_xor(p, m, 64);
    return pack_key(esq[v] - 2.0f * p, v);
}

__global__ __launch_bounds__(256) void k_gather(const float* __restrict__ h,
                                                const float* __restrict__ emb,
                                                const float* __restrict__ esq,
                                                const float* __restrict__ hsqp,
                                                const float* __restrict__ E2max,
                                                const u64* __restrict__ keys2,
                                                float* __restrict__ out0,
                                                float* __restrict__ out1,
                                                float* __restrict__ out2) {
    __shared__ float zq[32][260];
    __shared__ float wred[4];
    const int tid = threadIdx.x;
    const int lane = tid & 63;
    const int w = tid >> 6;
    const int n0 = blockIdx.x * 32;
    const int b = n0 >> 10;
    const int p0 = n0 & 1023;
    const float e2m = E2max[0];

    // refine: wave w owns rows w*8 .. w*8+7
#pragma unroll 1
    for (int rr = 0; rr < 8; ++rr) {
        const int rloc = w * 8 + rr, rg = n0 + rloc;
        // lane L holds key for bn = L>>1, slot = L&1
        u64 key = keys2[(size_t)(lane >> 1) * (NTOT * 2) + (size_t)rg * 2 + (lane & 1)];
        u64 gm = key;
#pragma unroll
        for (int m = 32; m >= 1; m >>= 1) {
            u64 o = __shfl_xor(gm, m, 64);
            gm = o < gm ? o : gm;
        }
        // sound error window: |approx_dist - true_dist| <= 2*B, B = 2^-10*1.02*||h||*||e||max
        float hq = 0.0f;
#pragma unroll
        for (int k = 0; k < 8; ++k) hq += hsqp[(size_t)(rg >> 8) * 2048 + k * 256 + (rg & 255)];
        const float thr = unpack_dist(gm) + 4.0e-3f * sqrtf(hq * e2m) + 1e-2f;
        u64 cmask = __ballot(unpack_dist(key) <= thr);
        u64 bestk = ~0ULL;
        while (cmask) {
            int L = __ffsll((long long)cmask) - 1;
            cmask &= cmask - 1;
            u64 kL = __shfl(key, L, 64);
            if (L & 1) {
                // block's 2nd-min inside window (rare): rescan its 128 candidates exactly
                int vb = (L >> 1) * 128;
                for (int v = vb; v < vb + 128; ++v) {
                    u64 ek = exact_key(h, emb, esq, rg, v, lane);
                    bestk = ek < bestk ? ek : bestk;
                }
            } else {
                u64 ek = exact_key(h, emb, esq, rg, (int)(kL & 0xFFFFFFFFu), lane);
                bestk = ek < bestk ? ek : bestk;
            }
        }
        const int bidx = (int)(bestk & 0xFFFFFFFFu);
        if (lane == 0) out1[rg] = (float)bidx;
        float4 e4 = *(const float4*)(emb + (size_t)bidx * D + lane * 4);
        *(float4*)&zq[rloc][lane * 4] = e4;
    }
    __syncthreads();

    float lsum = 0.0f;
    const size_t base = ((size_t)b * D) << 10;
#pragma unroll 4
    for (int it = 0; it < 32; ++it) {
        int c = it * 8 + (tid >> 5);
        int pp = tid & 31;
        float z = zq[pp][c];
        size_t g = base + ((size_t)c << 10) + p0 + pp;
        float hv = h[g];
        out0[g] = hv + (z - hv);
        float d = hv - z;
        lsum = fmaf(d, d, lsum);
    }
#pragma unroll
    for (int m = 32; m >= 1; m >>= 1) lsum += __shfl_xor(lsum, m, 64);
    if (lane == 0) wred[w] = lsum;
    __syncthreads();
    if (tid == 0)
        atomicAdd(out2, (wred[0] + wred[1] + wred[2] + wred[3]) * (1.0f / (float)N_OUT0));
}

extern "C" void kernel_launch(void* const* d_in, const int* in_sizes, int n_in,
                              void* d_out, int out_size, void* d_ws, size_t ws_size,
                              hipStream_t stream) {
    const float* h = (const float*)d_in[0];
    const float* emb = (const float*)d_in[1];
    float* out0 = (float*)d_out;
    float* out1 = out0 + N_OUT0;
    float* out2 = out1 + NTOT;

    // ws: Apk 8MB | Bpk 2MB | esq 16KB | hsqp 512KB | e2maxp 1KB | E2max 1KB | keys2 8MB
    //     total ~18.5MB (ws >= 21.1MB confirmed)
    char* wsb = (char*)d_ws;
    _Float16* Apk = (_Float16*)wsb;
    _Float16* Bpk = (_Float16*)(wsb + 8388608);
    float* esq = (float*)(wsb + 10485760);
    float* hsqp = (float*)(wsb + 10502144);
    float* e2maxp = (float*)(wsb + 11026432);
    float* E2max = (float*)(wsb + 11027456);
    u64* keys2 = (u64*)(wsb + 11028480);

    hipLaunchKernelGGL(k_prep, dim3(64), dim3(256), 0, stream, emb, esq, e2maxp, out2);
    hipLaunchKernelGGL(k_pack, dim3(769), dim3(256), 0, stream, h, emb, Apk, Bpk, hsqp, e2maxp, E2max);
    hipLaunchKernelGGL(k_gemm, dim3(4096), dim3(256), 0, stream, Apk, Bpk, esq, keys2);
    hipLaunchKernelGGL(k_gather, dim3(NTOT / 32), dim3(256), 0, stream, h, emb, esq, hsqp, E2max, keys2, out0, out1, out2);
}

// Round 6
// 303.474 us; speedup vs baseline: 1.0099x; 1.0099x over previous
//
#include <hip/hip_runtime.h>

#define D 256
#define VOCAB 4096
#define NTOT 16384      // 16 * 32 * 32
#define N_OUT0 4194304  // 16*256*32*32

typedef _Float16 half8 __attribute__((ext_vector_type(8)));
typedef float f32x4 __attribute__((ext_vector_type(4)));
typedef unsigned long long u64;

__device__ __forceinline__ void gld16(const void* g, void* l) {
    __builtin_amdgcn_global_load_lds(
        (const __attribute__((address_space(1))) void*)g,
        (__attribute__((address_space(3))) void*)l, 16, 0, 0);
}

__device__ __forceinline__ u64 pack_key(float d, int v) {
    unsigned u = __float_as_uint(d);
    u ^= ((unsigned)((int)u >> 31)) | 0x80000000u;  // monotonic float->uint
    return ((u64)u << 32) | (unsigned)v;
}

__device__ __forceinline__ float unpack_dist(u64 k) {
    unsigned u = (unsigned)(k >> 32);
    u = (u & 0x80000000u) ? (u ^ 0x80000000u) : ~u;
    return __uint_as_float(u);
}

// ---------------- prep: esq + per-block e2max partials + out2 zero ----------------
__global__ __launch_bounds__(256) void k_prep(const float* __restrict__ emb,
                                              float* __restrict__ esq,
                                              float* __restrict__ e2maxp,
                                              float* __restrict__ out2) {
    __shared__ float sm[4];
    const int tid = threadIdx.x, lane = tid & 63, wv = tid >> 6;
    const int v0 = blockIdx.x * 64;
    float lmax = 0.0f;
#pragma unroll 4
    for (int i = 0; i < 16; ++i) {
        int v = v0 + i * 4 + wv;
        float4 e = *(const float4*)(emb + (size_t)v * D + lane * 4);
        float s = e.x * e.x + e.y * e.y + e.z * e.z + e.w * e.w;
#pragma unroll
        for (int m = 32; m >= 1; m >>= 1) s += __shfl_xor(s, m, 64);
        if (lane == 0) esq[v] = s;
        lmax = fmaxf(lmax, s);
    }
    if (lane == 0) sm[wv] = lmax;
    __syncthreads();
    if (tid == 0) {
        e2maxp[blockIdx.x] = fmaxf(fmaxf(sm[0], sm[1]), fmaxf(sm[2], sm[3]));
        if (blockIdx.x == 0) out2[0] = 0.0f;
    }
}

// ---------------- fused pack (hi-only) + hsq partials + ht rows + E2max ----------------
// blocks 0..511: pack A (hi) + hsq partials + ht (row-major h_flat, stored IN out0 —
//   dead until k_out overwrites it; k_refine only READS it, k_out runs after);
// 512..767: pack B (hi); 768: E2max reduce
// Apk (halfs): [bm 64][w 8][q 4][r 256][j 8]   window = 8192 halfs
// Bpk (halfs): [bn 32][w 8][q 4][r 128][j 8]   window = 4096 halfs
__global__ __launch_bounds__(256) void k_pack(const float* __restrict__ h,
                                              const float* __restrict__ emb,
                                              _Float16* __restrict__ Apk,
                                              _Float16* __restrict__ Bpk,
                                              float* __restrict__ hsqp,
                                              float* __restrict__ ht,
                                              const float* __restrict__ e2maxp,
                                              float* __restrict__ E2max) {
    __shared__ float S[8192];
    const int tid = threadIdx.x;
    const int bid = blockIdx.x;
    if (bid < 512) {
        const int bm = bid >> 3, w = bid & 7;
        const int b = bm >> 2, p0 = (bm & 3) * 256;
        const float* src = h + ((size_t)b << 18) + p0;
#pragma unroll 4
        for (int cl = 0; cl < 32; ++cl)
            S[cl * 256 + tid] = src[(size_t)(w * 32 + cl) << 10 | (unsigned)tid];
        __syncthreads();
        // hsq partial for this 32-channel slice, row = tid (exact f32 h values)
        float sq = 0.0f;
#pragma unroll
        for (int cl = 0; cl < 32; ++cl) {
            float t = S[cl * 256 + tid];
            sq = fmaf(t, t, sq);
        }
        hsqp[(size_t)(bm * 8 + w) * 256 + tid] = sq;
        // ht: row-major h_flat slice ht[rg][w*32 .. w*32+31], rg = bm*256 + tid
        float* htr = ht + ((size_t)(bm * 256 + tid)) * D + w * 32;
#pragma unroll
        for (int c4 = 0; c4 < 8; ++c4) {
            float4 t;
            t.x = S[(c4 * 4 + 0) * 256 + tid];
            t.y = S[(c4 * 4 + 1) * 256 + tid];
            t.z = S[(c4 * 4 + 2) * 256 + tid];
            t.w = S[(c4 * 4 + 3) * 256 + tid];
            *(float4*)(htr + c4 * 4) = t;
        }
        _Float16* dstT = Apk + (size_t)bm * 65536 + (size_t)w * 8192;
#pragma unroll
        for (int i = 0; i < 4; ++i) {  // q = i, r = tid
            alignas(16) _Float16 hi[8];
#pragma unroll
            for (int j = 0; j < 8; ++j) hi[j] = (_Float16)S[(i * 8 + j) * 256 + tid];
            *(half8*)(dstT + i * 2048 + tid * 8) = *(half8*)hi;
        }
    } else if (bid < 768) {
        const int bid2 = bid - 512;
        const int bn = bid2 >> 3, w = bid2 & 7;
        const int v0 = bn * 128;
#pragma unroll 4
        for (int i = 0; i < 16; ++i) {
            int flat = i * 256 + tid;
            int r = flat >> 5, cl = flat & 31;
            S[cl * 129 + r] = emb[(size_t)(v0 + r) * D + w * 32 + cl];
        }
        __syncthreads();
        _Float16* dstT = Bpk + (size_t)bn * 32768 + (size_t)w * 4096;
#pragma unroll
        for (int i = 0; i < 2; ++i) {
            int s = i * 256 + tid;
            int q = s >> 7, r = s & 127;
            alignas(16) _Float16 hi[8];
#pragma unroll
            for (int j = 0; j < 8; ++j) hi[j] = (_Float16)S[(q * 8 + j) * 129 + r];
            *(half8*)(dstT + q * 1024 + r * 8) = *(half8*)hi;
        }
    } else {
        // E2max = max over 64 per-block partials (k_prep ran in a prior launch)
        if (tid < 64) {
            float m = e2maxp[tid];
#pragma unroll
            for (int s = 32; s >= 1; s >>= 1) m = fmaxf(m, __shfl_xor(m, s, 64));
            if (tid == 0) E2max[0] = m;
        }
    }
}

// ---------------- distance GEMM (single fp16 pass) + per-(row,bn) top-2 ----------------
// Tile 128m x 128n, 256 threads = 4 waves (2m x 2n), wave tile 64x64 = 4x4 frags.
// Triple-buffered LDS (As/Bs 3x8KB = 48KB -> 3 blocks/CU), counted vmcnt(4),
// raw barrier per window. 8 windows of K=32. Epilogue: per (row, bn) TOP-2 keys,
// ROW-MAJOR keys2[row][bn][slot] so the refine reads one row as 512B coalesced.

#define STAGE(W, BUF) do { \
    _Pragma("unroll") \
    for (int s_ = 0; s_ < 2; ++s_) { \
        int f_ = s_ * 256 + tid; \
        gld16(AgH + (W) * 8192 + (f_ >> 7) * 2048 + (f_ & 127) * 8, \
              As + (BUF) * 4096 + f_ * 8); \
    } \
    _Pragma("unroll") \
    for (int s_ = 0; s_ < 2; ++s_) { \
        int f_ = s_ * 256 + tid; \
        gld16(Bg + (W) * 4096 + f_ * 8, Bs + (BUF) * 4096 + f_ * 8); \
    } } while (0)

#define PHASE_END(N) do { \
    __builtin_amdgcn_sched_barrier(0); \
    asm volatile("s_waitcnt vmcnt(" #N ")" ::: "memory"); \
    __builtin_amdgcn_s_barrier(); } while (0)

#define WINDOW(BUF, DOSTAGE, SW, SBUF) do { \
    const _Float16* aB = As + (BUF) * 4096 + quad * 1024 + (wm * 64 + j16) * 8; \
    const _Float16* bB = Bs + (BUF) * 4096 + quad * 1024 + (wn * 64 + j16) * 8; \
    if (DOSTAGE) STAGE(SW, SBUF); \
    half8 af[4], bf[4]; \
    _Pragma("unroll") \
    for (int mt_ = 0; mt_ < 4; ++mt_) af[mt_] = *(const half8*)(aB + mt_ * 128); \
    _Pragma("unroll") \
    for (int nt_ = 0; nt_ < 4; ++nt_) bf[nt_] = *(const half8*)(bB + nt_ * 128); \
    __builtin_amdgcn_s_setprio(1); \
    _Pragma("unroll") \
    for (int mt_ = 0; mt_ < 4; ++mt_) { \
      _Pragma("unroll") \
      for (int nt_ = 0; nt_ < 4; ++nt_) \
        acc[mt_][nt_] = __builtin_amdgcn_mfma_f32_16x16x32_f16(af[mt_], bf[nt_], acc[mt_][nt_], 0, 0, 0); \
    } \
    __builtin_amdgcn_s_setprio(0); \
  } while (0)

__global__ __launch_bounds__(256, 3) void k_gemm(const _Float16* __restrict__ Apk,
                                                 const _Float16* __restrict__ Bpk,
                                                 const float* __restrict__ esq,
                                                 u64* __restrict__ keys2) {
    __shared__ alignas(16) _Float16 As[12288];  // 3 x [q 4][r 128][j 8] = 24KB
    __shared__ alignas(16) _Float16 Bs[12288];  // 3 x [q 4][r 128][j 8] = 24KB

    const int tid = threadIdx.x;
    const int bid = blockIdx.x;
    // XCD-chunked bijective swizzle (4096 % 8 == 0); bn fastest for A-panel L2 reuse
    const int swz = (bid & 7) * 512 + (bid >> 3);
    const int bm = swz >> 5, bn = swz & 31;
    const int m0 = bm * 128, n0 = bn * 128;

    // Apk panels are 256 rows: this block takes half (bm&1) of panel bm>>1
    const _Float16* AgH = Apk + (size_t)(bm >> 1) * 65536 + (size_t)(bm & 1) * 1024;
    const _Float16* Bg = Bpk + (size_t)bn * 32768;

    STAGE(0, 0);
    STAGE(1, 1);

    const int wv = tid >> 6, l = tid & 63;
    const int wm = wv & 1, wn = wv >> 1;
    const int quad = l >> 4, j16 = l & 15;

    f32x4 acc[4][4];
#pragma unroll
    for (int i = 0; i < 4; ++i)
#pragma unroll
        for (int j = 0; j < 4; ++j) acc[i][j] = (f32x4)0.0f;

    asm volatile("s_waitcnt vmcnt(4)" ::: "memory");  // window 0 landed; w1 in flight
    __builtin_amdgcn_s_barrier();

    WINDOW(0, 1, 2, 2); PHASE_END(4);   // w0; stage w2; wait: w1 ready
    WINDOW(1, 1, 3, 0); PHASE_END(4);   // w1; stage w3; wait: w2 ready
    WINDOW(2, 1, 4, 1); PHASE_END(4);
    WINDOW(0, 1, 5, 2); PHASE_END(4);
    WINDOW(1, 1, 6, 0); PHASE_END(4);
    WINDOW(2, 1, 7, 1); PHASE_END(4);
    WINDOW(0, 0, 0, 0); PHASE_END(0);   // w6; wait: w7 ready
    WINDOW(1, 0, 0, 0);                 // w7
    __syncthreads();                    // all MFMA reads done; As reusable

    // epilogue: per-(row, bn) top-2 of approx dist keys
    u64* t2 = (u64*)As;  // [128][wn 2][2] = 4KB, aliases dead As
    float es[4];
    int vidx[4];
#pragma unroll
    for (int nt = 0; nt < 4; ++nt) {
        vidx[nt] = n0 + wn * 64 + nt * 16 + j16;
        es[nt] = esq[vidx[nt]];
    }
#pragma unroll
    for (int mt = 0; mt < 4; ++mt) {
#pragma unroll
        for (int r = 0; r < 4; ++r) {
            u64 m1 = ~0ULL, m2 = ~0ULL;
#pragma unroll
            for (int nt = 0; nt < 4; ++nt) {
                float dv = es[nt] - 2.0f * acc[mt][nt][r];
                u64 k = pack_key(dv, vidx[nt]);
                if (k < m1) { m2 = m1; m1 = k; }
                else if (k < m2) { m2 = k; }
            }
#pragma unroll
            for (int m = 8; m >= 1; m >>= 1) {
                u64 o1 = __shfl_xor(m1, m, 64), o2 = __shfl_xor(m2, m, 64);
                u64 hi = m1 > o1 ? m1 : o1;
                m1 = m1 < o1 ? m1 : o1;
                u64 lo2 = m2 < o2 ? m2 : o2;
                m2 = hi < lo2 ? hi : lo2;
            }
            if (j16 == 0) {
                int row = wm * 64 + mt * 16 + quad * 4 + r;
                t2[row * 4 + wn * 2 + 0] = m1;
                t2[row * 4 + wn * 2 + 1] = m2;
            }
        }
    }
    __syncthreads();
    if (tid < 128) {
        u64 a1 = t2[tid * 4 + 0], a2 = t2[tid * 4 + 1];
        u64 b1 = t2[tid * 4 + 2], b2 = t2[tid * 4 + 3];
        u64 M1 = a1 < b1 ? a1 : b1;
        u64 x = a1 < b1 ? b1 : a1;
        u64 y = a2 < b2 ? a2 : b2;
        u64 M2 = x < y ? x : y;
        // row-major: keys2[row][bn][slot]
        keys2[(size_t)(m0 + tid) * 64 + bn * 2 + 0] = M1;
        keys2[(size_t)(m0 + tid) * 64 + bn * 2 + 1] = M2;
    }
}

// ---------------- refine: windowed exact argmin -> out1 (READS out0-as-ht only) ----------------
__device__ __forceinline__ u64 exact_key_ht(const float* __restrict__ ht,
                                            const float* __restrict__ emb,
                                            const float* __restrict__ esq,
                                            int rg, int v, int lane) {
    const float4 h4 = *(const float4*)(ht + (size_t)rg * D + lane * 4);
    const float4 e4 = *(const float4*)(emb + (size_t)v * D + lane * 4);
    float p = h4.x * e4.x;
    p = fmaf(h4.y, e4.y, p);
    p = fmaf(h4.z, e4.z, p);
    p = fmaf(h4.w, e4.w, p);
#pragma unroll
    for (int m = 32; m >= 1; m >>= 1) p += __shfl_xor(p, m, 64);
    return pack_key(esq[v] - 2.0f * p, v);
}

__global__ __launch_bounds__(256) void k_refine(const float* __restrict__ ht,  // = out0
                                                const float* __restrict__ emb,
                                                const float* __restrict__ esq,
                                                const float* __restrict__ hsqp,
                                                const float* __restrict__ E2max,
                                                const u64* __restrict__ keys2,
                                                float* __restrict__ out1) {
    const int tid = threadIdx.x;
    const int lane = tid & 63;
    const int w = tid >> 6;
    const int n0 = blockIdx.x * 32;
    const float e2m = E2max[0];

    // wave w owns rows w*8 .. w*8+7
#pragma unroll 1
    for (int rr = 0; rr < 8; ++rr) {
        const int rg = n0 + w * 8 + rr;
        // lane L holds key for bn = L>>1, slot = L&1 (coalesced 512B row)
        u64 key = keys2[(size_t)rg * 64 + lane];
        u64 gm = key;
#pragma unroll
        for (int m = 32; m >= 1; m >>= 1) {
            u64 o = __shfl_xor(gm, m, 64);
            gm = o < gm ? o : gm;
        }
        // sound error window: |approx - true| <= B ~= 2e-3*||h||*||e||max; thr = gm+2B+slack
        float hq = 0.0f;
#pragma unroll
        for (int k = 0; k < 8; ++k) hq += hsqp[(size_t)(rg >> 8) * 2048 + k * 256 + (rg & 255)];
        const float thr = unpack_dist(gm) + 4.0e-3f * sqrtf(hq * e2m) + 1e-2f;
        u64 cmask = __ballot(unpack_dist(key) <= thr);
        u64 bestk;
        if (__popcll(cmask) == 1) {
            // fast path: only gmin is in-window among stored keys; every block's
            // unstored (rank>=3) keys >= its stored slot-1 key > thr => gmin exact.
            bestk = gm;
        } else {
            bestk = ~0ULL;
            while (cmask) {
                int L = __ffsll((long long)cmask) - 1;
                cmask &= cmask - 1;
                u64 kL = __shfl(key, L, 64);
                if (L & 1) {
                    // block's 2nd-min inside window (rare): rescan its 128 candidates
                    int vb = (L >> 1) * 128;
                    for (int v = vb; v < vb + 128; ++v) {
                        u64 ek = exact_key_ht(ht, emb, esq, rg, v, lane);
                        bestk = ek < bestk ? ek : bestk;
                    }
                } else {
                    u64 ek = exact_key_ht(ht, emb, esq, rg, (int)(kL & 0xFFFFFFFFu), lane);
                    bestk = ek < bestk ? ek : bestk;
                }
            }
        }
        if (lane == 0) out1[rg] = (float)(int)(bestk & 0xFFFFFFFFu);
    }
}

// ---------------- out: gather emb by index, write z_q_st (overwrites ht) + loss ----------------
// Separate launch AFTER k_refine: kernel boundary guarantees every block's ht reads
// finished before any out0 overwrite (this was the round-5 race).
__global__ __launch_bounds__(256) void k_out(const float* __restrict__ h,
                                             const float* __restrict__ emb,
                                             const float* __restrict__ out1,
                                             float* __restrict__ out0,
                                             float* __restrict__ out2) {
    __shared__ float zq[32][260];
    __shared__ float wred[4];
    const int tid = threadIdx.x;
    const int lane = tid & 63;
    const int w = tid >> 6;
    const int n0 = blockIdx.x * 32;
    const int b = n0 >> 10;
    const int p0 = n0 & 1023;
#pragma unroll
    for (int rr = 0; rr < 8; ++rr) {
        int r = w * 8 + rr;
        unsigned idx = (unsigned)(int)out1[n0 + r];
        float4 e4 = *(const float4*)(emb + (size_t)idx * D + lane * 4);
        *(float4*)&zq[r][lane * 4] = e4;
    }
    __syncthreads();
    float lsum = 0.0f;
    const size_t base = ((size_t)b * D) << 10;
#pragma unroll 4
    for (int it = 0; it < 32; ++it) {
        int c = it * 8 + (tid >> 5);
        int pp = tid & 31;
        float z = zq[pp][c];
        size_t g = base + ((size_t)c << 10) + p0 + pp;
        float hv = h[g];
        out0[g] = hv + (z - hv);
        float d = hv - z;
        lsum = fmaf(d, d, lsum);
    }
#pragma unroll
    for (int m = 32; m >= 1; m >>= 1) lsum += __shfl_xor(lsum, m, 64);
    if (lane == 0) wred[w] = lsum;
    __syncthreads();
    if (tid == 0)
        atomicAdd(out2, (wred[0] + wred[1] + wred[2] + wred[3]) * (1.0f / (float)N_OUT0));
}

extern "C" void kernel_launch(void* const* d_in, const int* in_sizes, int n_in,
                              void* d_out, int out_size, void* d_ws, size_t ws_size,
                              hipStream_t stream) {
    const float* h = (const float*)d_in[0];
    const float* emb = (const float*)d_in[1];
    float* out0 = (float*)d_out;
    float* out1 = out0 + N_OUT0;
    float* out2 = out1 + NTOT;

    // ws: Apk 8MB | Bpk 2MB | esq 16KB | hsqp 512KB | e2maxp 1KB | E2max 1KB | keys2 8MB
    //     total ~18.5MB (ws >= 21.1MB confirmed). ht (16MB) lives in out0 until k_out.
    char* wsb = (char*)d_ws;
    _Float16* Apk = (_Float16*)wsb;
    _Float16* Bpk = (_Float16*)(wsb + 8388608);
    float* esq = (float*)(wsb + 10485760);
    float* hsqp = (float*)(wsb + 10502144);
    float* e2maxp = (float*)(wsb + 11026432);
    float* E2max = (float*)(wsb + 11027456);
    u64* keys2 = (u64*)(wsb + 11028480);

    hipLaunchKernelGGL(k_prep, dim3(64), dim3(256), 0, stream, emb, esq, e2maxp, out2);
    hipLaunchKernelGGL(k_pack, dim3(769), dim3(256), 0, stream, h, emb, Apk, Bpk, hsqp, out0, e2maxp, E2max);
    hipLaunchKernelGGL(k_gemm, dim3(4096), dim3(256), 0, stream, Apk, Bpk, esq, keys2);
    hipLaunchKernelGGL(k_refine, dim3(NTOT / 32), dim3(256), 0, stream, out0, emb, esq, hsqp, E2max, keys2, out1);
    hipLaunchKernelGGL(k_out, dim3(NTOT / 32), dim3(256), 0, stream, h, emb, out1, out0, out2);
}

// Round 7
// 212.379 us; speedup vs baseline: 1.4431x; 1.4289x over previous
//
#include <hip/hip_runtime.h>

#define D 256
#define VOCAB 4096
#define NTOT 16384      // 16 * 32 * 32
#define N_OUT0 4194304  // 16*256*32*32

typedef _Float16 half8 __attribute__((ext_vector_type(8)));
typedef float f32x4 __attribute__((ext_vector_type(4)));
typedef unsigned long long u64;

__device__ __forceinline__ void gld16(const void* g, void* l) {
    __builtin_amdgcn_global_load_lds(
        (const __attribute__((address_space(1))) void*)g,
        (__attribute__((address_space(3))) void*)l, 16, 0, 0);
}

__device__ __forceinline__ u64 pack_key(float d, int v) {
    unsigned u = __float_as_uint(d);
    u ^= ((unsigned)((int)u >> 31)) | 0x80000000u;  // monotonic float->uint
    return ((u64)u << 32) | (unsigned)v;
}

__device__ __forceinline__ float unpack_dist(u64 k) {
    unsigned u = (unsigned)(k >> 32);
    u = (u & 0x80000000u) ? (u ^ 0x80000000u) : ~u;
    return __uint_as_float(u);
}

// ---------------- prep: esq + per-block e2max partials + out2 zero ----------------
__global__ __launch_bounds__(256) void k_prep(const float* __restrict__ emb,
                                              float* __restrict__ esq,
                                              float* __restrict__ e2maxp,
                                              float* __restrict__ out2) {
    __shared__ float sm[4];
    const int tid = threadIdx.x, lane = tid & 63, wv = tid >> 6;
    const int v0 = blockIdx.x * 64;
    float lmax = 0.0f;
#pragma unroll 4
    for (int i = 0; i < 16; ++i) {
        int v = v0 + i * 4 + wv;
        float4 e = *(const float4*)(emb + (size_t)v * D + lane * 4);
        float s = e.x * e.x + e.y * e.y + e.z * e.z + e.w * e.w;
#pragma unroll
        for (int m = 32; m >= 1; m >>= 1) s += __shfl_xor(s, m, 64);
        if (lane == 0) esq[v] = s;
        lmax = fmaxf(lmax, s);
    }
    if (lane == 0) sm[wv] = lmax;
    __syncthreads();
    if (tid == 0) {
        e2maxp[blockIdx.x] = fmaxf(fmaxf(sm[0], sm[1]), fmaxf(sm[2], sm[3]));
        if (blockIdx.x == 0) out2[0] = 0.0f;
    }
}

// ---------------- fused pack (hi-only) + hsq partials + ht rows + E2max ----------------
// blocks 0..511: pack A (hi) + hsq partials + ht (row-major h_flat, stored IN out0 —
//   dead until k_out overwrites it; k_refine only READS it, k_out runs after);
// 512..767: pack B (hi); 768: E2max reduce
// Apk (halfs): [bm 64][w 8][q 4][r 256][j 8]   window = 8192 halfs
// Bpk (halfs): [bn 32][w 8][q 4][r 128][j 8]   window = 4096 halfs
__global__ __launch_bounds__(256) void k_pack(const float* __restrict__ h,
                                              const float* __restrict__ emb,
                                              _Float16* __restrict__ Apk,
                                              _Float16* __restrict__ Bpk,
                                              float* __restrict__ hsqp,
                                              float* __restrict__ ht,
                                              const float* __restrict__ e2maxp,
                                              float* __restrict__ E2max) {
    __shared__ float S[8192];
    const int tid = threadIdx.x;
    const int bid = blockIdx.x;
    if (bid < 512) {
        const int bm = bid >> 3, w = bid & 7;
        const int b = bm >> 2, p0 = (bm & 3) * 256;
        const float* src = h + ((size_t)b << 18) + p0;
#pragma unroll 4
        for (int cl = 0; cl < 32; ++cl)
            S[cl * 256 + tid] = src[(size_t)(w * 32 + cl) << 10 | (unsigned)tid];
        __syncthreads();
        // hsq partial for this 32-channel slice, row = tid (exact f32 h values)
        float sq = 0.0f;
#pragma unroll
        for (int cl = 0; cl < 32; ++cl) {
            float t = S[cl * 256 + tid];
            sq = fmaf(t, t, sq);
        }
        hsqp[(size_t)(bm * 8 + w) * 256 + tid] = sq;
        // ht: row-major h_flat slice ht[rg][w*32 .. w*32+31], rg = bm*256 + tid
        float* htr = ht + ((size_t)(bm * 256 + tid)) * D + w * 32;
#pragma unroll
        for (int c4 = 0; c4 < 8; ++c4) {
            float4 t;
            t.x = S[(c4 * 4 + 0) * 256 + tid];
            t.y = S[(c4 * 4 + 1) * 256 + tid];
            t.z = S[(c4 * 4 + 2) * 256 + tid];
            t.w = S[(c4 * 4 + 3) * 256 + tid];
            *(float4*)(htr + c4 * 4) = t;
        }
        _Float16* dstT = Apk + (size_t)bm * 65536 + (size_t)w * 8192;
#pragma unroll
        for (int i = 0; i < 4; ++i) {  // q = i, r = tid
            alignas(16) _Float16 hi[8];
#pragma unroll
            for (int j = 0; j < 8; ++j) hi[j] = (_Float16)S[(i * 8 + j) * 256 + tid];
            *(half8*)(dstT + i * 2048 + tid * 8) = *(half8*)hi;
        }
    } else if (bid < 768) {
        const int bid2 = bid - 512;
        const int bn = bid2 >> 3, w = bid2 & 7;
        const int v0 = bn * 128;
#pragma unroll 4
        for (int i = 0; i < 16; ++i) {
            int flat = i * 256 + tid;
            int r = flat >> 5, cl = flat & 31;
            S[cl * 129 + r] = emb[(size_t)(v0 + r) * D + w * 32 + cl];
        }
        __syncthreads();
        _Float16* dstT = Bpk + (size_t)bn * 32768 + (size_t)w * 4096;
#pragma unroll
        for (int i = 0; i < 2; ++i) {
            int s = i * 256 + tid;
            int q = s >> 7, r = s & 127;
            alignas(16) _Float16 hi[8];
#pragma unroll
            for (int j = 0; j < 8; ++j) hi[j] = (_Float16)S[(q * 8 + j) * 129 + r];
            *(half8*)(dstT + q * 1024 + r * 8) = *(half8*)hi;
        }
    } else {
        // E2max = max over 64 per-block partials (k_prep ran in a prior launch)
        if (tid < 64) {
            float m = e2maxp[tid];
#pragma unroll
            for (int s = 32; s >= 1; s >>= 1) m = fmaxf(m, __shfl_xor(m, s, 64));
            if (tid == 0) E2max[0] = m;
        }
    }
}

// ---------------- distance GEMM (single fp16 pass) + per-(row,bn) top-2 ----------------
// Tile 128m x 128n, 256 threads = 4 waves (2m x 2n), wave tile 64x64 = 4x4 frags.
// Triple-buffered LDS (As/Bs 3x8KB = 48KB -> 3 blocks/CU), counted vmcnt(4),
// raw barrier per window. 8 windows of K=32. Epilogue: per (row, bn) TOP-2 keys,
// ROW-MAJOR keys2[row][bn][slot] so the refine reads one row as 512B coalesced.

#define STAGE(W, BUF) do { \
    _Pragma("unroll") \
    for (int s_ = 0; s_ < 2; ++s_) { \
        int f_ = s_ * 256 + tid; \
        gld16(AgH + (W) * 8192 + (f_ >> 7) * 2048 + (f_ & 127) * 8, \
              As + (BUF) * 4096 + f_ * 8); \
    } \
    _Pragma("unroll") \
    for (int s_ = 0; s_ < 2; ++s_) { \
        int f_ = s_ * 256 + tid; \
        gld16(Bg + (W) * 4096 + f_ * 8, Bs + (BUF) * 4096 + f_ * 8); \
    } } while (0)

#define PHASE_END(N) do { \
    __builtin_amdgcn_sched_barrier(0); \
    asm volatile("s_waitcnt vmcnt(" #N ")" ::: "memory"); \
    __builtin_amdgcn_s_barrier(); } while (0)

#define WINDOW(BUF, DOSTAGE, SW, SBUF) do { \
    const _Float16* aB = As + (BUF) * 4096 + quad * 1024 + (wm * 64 + j16) * 8; \
    const _Float16* bB = Bs + (BUF) * 4096 + quad * 1024 + (wn * 64 + j16) * 8; \
    if (DOSTAGE) STAGE(SW, SBUF); \
    half8 af[4], bf[4]; \
    _Pragma("unroll") \
    for (int mt_ = 0; mt_ < 4; ++mt_) af[mt_] = *(const half8*)(aB + mt_ * 128); \
    _Pragma("unroll") \
    for (int nt_ = 0; nt_ < 4; ++nt_) bf[nt_] = *(const half8*)(bB + nt_ * 128); \
    __builtin_amdgcn_s_setprio(1); \
    _Pragma("unroll") \
    for (int mt_ = 0; mt_ < 4; ++mt_) { \
      _Pragma("unroll") \
      for (int nt_ = 0; nt_ < 4; ++nt_) \
        acc[mt_][nt_] = __builtin_amdgcn_mfma_f32_16x16x32_f16(af[mt_], bf[nt_], acc[mt_][nt_], 0, 0, 0); \
    } \
    __builtin_amdgcn_s_setprio(0); \
  } while (0)

__global__ __launch_bounds__(256, 3) void k_gemm(const _Float16* __restrict__ Apk,
                                                 const _Float16* __restrict__ Bpk,
                                                 const float* __restrict__ esq,
                                                 u64* __restrict__ keys2) {
    __shared__ alignas(16) _Float16 As[12288];  // 3 x [q 4][r 128][j 8] = 24KB
    __shared__ alignas(16) _Float16 Bs[12288];  // 3 x [q 4][r 128][j 8] = 24KB

    const int tid = threadIdx.x;
    const int bid = blockIdx.x;
    // XCD-chunked bijective swizzle (4096 % 8 == 0); bn fastest for A-panel L2 reuse
    const int swz = (bid & 7) * 512 + (bid >> 3);
    const int bm = swz >> 5, bn = swz & 31;
    const int m0 = bm * 128, n0 = bn * 128;

    // Apk panels are 256 rows: this block takes half (bm&1) of panel bm>>1
    const _Float16* AgH = Apk + (size_t)(bm >> 1) * 65536 + (size_t)(bm & 1) * 1024;
    const _Float16* Bg = Bpk + (size_t)bn * 32768;

    STAGE(0, 0);
    STAGE(1, 1);

    const int wv = tid >> 6, l = tid & 63;
    const int wm = wv & 1, wn = wv >> 1;
    const int quad = l >> 4, j16 = l & 15;

    f32x4 acc[4][4];
#pragma unroll
    for (int i = 0; i < 4; ++i)
#pragma unroll
        for (int j = 0; j < 4; ++j) acc[i][j] = (f32x4)0.0f;

    asm volatile("s_waitcnt vmcnt(4)" ::: "memory");  // window 0 landed; w1 in flight
    __builtin_amdgcn_s_barrier();

    WINDOW(0, 1, 2, 2); PHASE_END(4);   // w0; stage w2; wait: w1 ready
    WINDOW(1, 1, 3, 0); PHASE_END(4);   // w1; stage w3; wait: w2 ready
    WINDOW(2, 1, 4, 1); PHASE_END(4);
    WINDOW(0, 1, 5, 2); PHASE_END(4);
    WINDOW(1, 1, 6, 0); PHASE_END(4);
    WINDOW(2, 1, 7, 1); PHASE_END(4);
    WINDOW(0, 0, 0, 0); PHASE_END(0);   // w6; wait: w7 ready
    WINDOW(1, 0, 0, 0);                 // w7
    __syncthreads();                    // all MFMA reads done; As reusable

    // epilogue: per-(row, bn) top-2 of approx dist keys
    u64* t2 = (u64*)As;  // [128][wn 2][2] = 4KB, aliases dead As
    float es[4];
    int vidx[4];
#pragma unroll
    for (int nt = 0; nt < 4; ++nt) {
        vidx[nt] = n0 + wn * 64 + nt * 16 + j16;
        es[nt] = esq[vidx[nt]];
    }
#pragma unroll
    for (int mt = 0; mt < 4; ++mt) {
#pragma unroll
        for (int r = 0; r < 4; ++r) {
            u64 m1 = ~0ULL, m2 = ~0ULL;
#pragma unroll
            for (int nt = 0; nt < 4; ++nt) {
                float dv = es[nt] - 2.0f * acc[mt][nt][r];
                u64 k = pack_key(dv, vidx[nt]);
                if (k < m1) { m2 = m1; m1 = k; }
                else if (k < m2) { m2 = k; }
            }
#pragma unroll
            for (int m = 8; m >= 1; m >>= 1) {
                u64 o1 = __shfl_xor(m1, m, 64), o2 = __shfl_xor(m2, m, 64);
                u64 hi = m1 > o1 ? m1 : o1;
                m1 = m1 < o1 ? m1 : o1;
                u64 lo2 = m2 < o2 ? m2 : o2;
                m2 = hi < lo2 ? hi : lo2;
            }
            if (j16 == 0) {
                int row = wm * 64 + mt * 16 + quad * 4 + r;
                t2[row * 4 + wn * 2 + 0] = m1;
                t2[row * 4 + wn * 2 + 1] = m2;
            }
        }
    }
    __syncthreads();
    if (tid < 128) {
        u64 a1 = t2[tid * 4 + 0], a2 = t2[tid * 4 + 1];
        u64 b1 = t2[tid * 4 + 2], b2 = t2[tid * 4 + 3];
        u64 M1 = a1 < b1 ? a1 : b1;
        u64 x = a1 < b1 ? b1 : a1;
        u64 y = a2 < b2 ? a2 : b2;
        u64 M2 = x < y ? x : y;
        // row-major: keys2[row][bn][slot]
        keys2[(size_t)(m0 + tid) * 64 + bn * 2 + 0] = M1;
        keys2[(size_t)(m0 + tid) * 64 + bn * 2 + 1] = M2;
    }
}

// ---------------- refine: windowed exact argmin -> out1 (READS out0-as-ht only) ----------------
__device__ __forceinline__ u64 exact_key_ht(const float* __restrict__ ht,
                                            const float* __restrict__ emb,
                                            const float* __restrict__ esq,
                                            int rg, int v, int lane) {
    const float4 h4 = *(const float4*)(ht + (size_t)rg * D + lane * 4);
    const float4 e4 = *(const float4*)(emb + (size_t)v * D + lane * 4);
    float p = h4.x * e4.x;
    p = fmaf(h4.y, e4.y, p);
    p = fmaf(h4.z, e4.z, p);
    p = fmaf(h4.w, e4.w, p);
#pragma unroll
    for (int m = 32; m >= 1; m >>= 1) p += __shfl_xor(p, m, 64);
    return pack_key(esq[v] - 2.0f * p, v);
}

__global__ __launch_bounds__(256) void k_refine(const float* __restrict__ ht,  // = out0
                                                const float* __restrict__ emb,
                                                const float* __restrict__ esq,
                                                const float* __restrict__ hsqp,
                                                const float* __restrict__ E2max,
                                                const u64* __restrict__ keys2,
                                                float* __restrict__ out1) {
    const int tid = threadIdx.x;
    const int lane = tid & 63;
    const int w = tid >> 6;
    const int n0 = blockIdx.x * 32;
    const float e2m = E2max[0];

    // wave w owns rows w*8 .. w*8+7; prefetch next row's keys under current reduce
    int rg = n0 + w * 8;
    u64 key = keys2[(size_t)rg * 64 + lane];
#pragma unroll 1
    for (int rr = 0; rr < 8; ++rr, ++rg) {
        u64 keyn = 0;
        if (rr < 7) keyn = keys2[(size_t)(rg + 1) * 64 + lane];
        u64 gm = key;
#pragma unroll
        for (int m = 32; m >= 1; m >>= 1) {
            u64 o = __shfl_xor(gm, m, 64);
            gm = o < gm ? o : gm;
        }
        // sound error window: |approx - true| <= B = 2^-9*||h||*||e||max; thr = gm+2B+slack
        float hq = 0.0f;
#pragma unroll
        for (int k = 0; k < 8; ++k) hq += hsqp[(size_t)(rg >> 8) * 2048 + k * 256 + (rg & 255)];
        const float thr = unpack_dist(gm) + 4.0e-3f * sqrtf(hq * e2m) + 1e-2f;
        u64 cmask = __ballot(unpack_dist(key) <= thr);
        u64 bestk;
        if (__popcll(cmask) == 1) {
            // fast path: only gmin is in-window among stored keys; every block's
            // unstored (rank>=3) keys >= its stored slot-1 key > thr => gmin exact.
            bestk = gm;
        } else {
            bestk = ~0ULL;
            u64 rescan = 0;  // bn set whose slot-1 is in-window (rank>=3 unknown)
            u64 cm = cmask;
            while (cm) {
                int L = __ffsll((long long)cm) - 1;
                cm &= cm - 1;
                if (L & 1) {
                    rescan |= 1ull << (L >> 1);
                } else {
                    u64 kL = __shfl(key, L, 64);
                    u64 ek = exact_key_ht(ht, emb, esq, rg, (int)(kL & 0xFFFFFFFFu), lane);
                    bestk = ek < bestk ? ek : bestk;
                }
            }
            // rare path, now LANE-PARALLEL (was: 128 serial wave-dots = 80us tail!).
            // 64 lanes x 2 candidates each, serial f32 dot (h row broadcast, emb from
            // L2), top-2 wave reduce, then exact re-eval of the 2 survivors so all
            // final comparisons share exact_key_ht rounding.
            while (rescan) {
                int bn = __ffsll((long long)rescan) - 1;
                rescan &= rescan - 1;
                const float* htr = ht + (size_t)rg * D;
                u64 k0 = ~0ULL, k1 = ~0ULL;
#pragma unroll
                for (int c = 0; c < 2; ++c) {
                    int v = bn * 128 + c * 64 + lane;
                    float p = 0.0f;
#pragma unroll 8
                    for (int d = 0; d < D; d += 4) {
                        float4 hh = *(const float4*)(htr + d);
                        float4 ee = *(const float4*)(emb + (size_t)v * D + d);
                        p = fmaf(hh.x, ee.x, p);
                        p = fmaf(hh.y, ee.y, p);
                        p = fmaf(hh.z, ee.z, p);
                        p = fmaf(hh.w, ee.w, p);
                    }
                    u64 kc = pack_key(esq[v] - 2.0f * p, v);
                    if (c == 0) k0 = kc; else k1 = kc;
                }
                u64 m1 = k0 < k1 ? k0 : k1, m2 = k0 < k1 ? k1 : k0;
#pragma unroll
                for (int m = 32; m >= 1; m >>= 1) {
                    u64 o1 = __shfl_xor(m1, m, 64), o2 = __shfl_xor(m2, m, 64);
                    u64 hi = m1 > o1 ? m1 : o1;
                    m1 = m1 < o1 ? m1 : o1;
                    u64 lo2 = m2 < o2 ? m2 : o2;
                    m2 = hi < lo2 ? hi : lo2;
                }
                u64 e1 = exact_key_ht(ht, emb, esq, rg, (int)(m1 & 0xFFFFFFFFu), lane);
                u64 e2 = exact_key_ht(ht, emb, esq, rg, (int)(m2 & 0xFFFFFFFFu), lane);
                bestk = e1 < bestk ? e1 : bestk;
                bestk = e2 < bestk ? e2 : bestk;
            }
        }
        if (lane == 0) out1[rg] = (float)(int)(bestk & 0xFFFFFFFFu);
        key = keyn;
    }
}

// ---------------- out: gather emb by index, write z_q_st (overwrites ht) + loss ----------------
// Separate launch AFTER k_refine: kernel boundary guarantees every block's ht reads
// finished before any out0 overwrite.
__global__ __launch_bounds__(256) void k_out(const float* __restrict__ h,
                                             const float* __restrict__ emb,
                                             const float* __restrict__ out1,
                                             float* __restrict__ out0,
                                             float* __restrict__ out2) {
    __shared__ float zq[32][260];
    __shared__ float wred[4];
    const int tid = threadIdx.x;
    const int lane = tid & 63;
    const int w = tid >> 6;
    const int n0 = blockIdx.x * 32;
    const int b = n0 >> 10;
    const int p0 = n0 & 1023;
#pragma unroll
    for (int rr = 0; rr < 8; ++rr) {
        int r = w * 8 + rr;
        unsigned idx = (unsigned)(int)out1[n0 + r];
        float4 e4 = *(const float4*)(emb + (size_t)idx * D + lane * 4);
        *(float4*)&zq[r][lane * 4] = e4;
    }
    __syncthreads();
    float lsum = 0.0f;
    const size_t base = ((size_t)b * D) << 10;
#pragma unroll 4
    for (int it = 0; it < 32; ++it) {
        int c = it * 8 + (tid >> 5);
        int pp = tid & 31;
        float z = zq[pp][c];
        size_t g = base + ((size_t)c << 10) + p0 + pp;
        float hv = h[g];
        out0[g] = hv + (z - hv);
        float d = hv - z;
        lsum = fmaf(d, d, lsum);
    }
#pragma unroll
    for (int m = 32; m >= 1; m >>= 1) lsum += __shfl_xor(lsum, m, 64);
    if (lane == 0) wred[w] = lsum;
    __syncthreads();
    if (tid == 0)
        atomicAdd(out2, (wred[0] + wred[1] + wred[2] + wred[3]) * (1.0f / (float)N_OUT0));
}

extern "C" void kernel_launch(void* const* d_in, const int* in_sizes, int n_in,
                              void* d_out, int out_size, void* d_ws, size_t ws_size,
                              hipStream_t stream) {
    const float* h = (const float*)d_in[0];
    const float* emb = (const float*)d_in[1];
    float* out0 = (float*)d_out;
    float* out1 = out0 + N_OUT0;
    float* out2 = out1 + NTOT;

    // ws: Apk 8MB | Bpk 2MB | esq 16KB | hsqp 512KB | e2maxp 1KB | E2max 1KB | keys2 8MB
    //     total ~18.5MB (ws >= 21.1MB confirmed). ht (16MB) lives in out0 until k_out.
    char* wsb = (char*)d_ws;
    _Float16* Apk = (_Float16*)wsb;
    _Float16* Bpk = (_Float16*)(wsb + 8388608);
    float* esq = (float*)(wsb + 10485760);
    float* hsqp = (float*)(wsb + 10502144);
    float* e2maxp = (float*)(wsb + 11026432);
    float* E2max = (float*)(wsb + 11027456);
    u64* keys2 = (u64*)(wsb + 11028480);

    hipLaunchKernelGGL(k_prep, dim3(64), dim3(256), 0, stream, emb, esq, e2maxp, out2);
    hipLaunchKernelGGL(k_pack, dim3(769), dim3(256), 0, stream, h, emb, Apk, Bpk, hsqp, out0, e2maxp, E2max);
    hipLaunchKernelGGL(k_gemm, dim3(4096), dim3(256), 0, stream, Apk, Bpk, esq, keys2);
    hipLaunchKernelGGL(k_refine, dim3(NTOT / 32), dim3(256), 0, stream, out0, emb, esq, hsqp, E2max, keys2, out1);
    hipLaunchKernelGGL(k_out, dim3(NTOT / 32), dim3(256), 0, stream, h, emb, out1, out0, out2);
}

// Round 9
// 190.033 us; speedup vs baseline: 1.6128x; 1.1176x over previous
//
#include <hip/hip_runtime.h>

#define D 256
#define VOCAB 4096
#define NTOT 16384      // 16 * 32 * 32
#define N_OUT0 4194304  // 16*256*32*32

typedef _Float16 half8 __attribute__((ext_vector_type(8)));
typedef float f32x4 __attribute__((ext_vector_type(4)));
typedef unsigned long long u64;

__device__ __forceinline__ void gld16(const void* g, void* l) {
    __builtin_amdgcn_global_load_lds(
        (const __attribute__((address_space(1))) void*)g,
        (__attribute__((address_space(3))) void*)l, 16, 0, 0);
}

__device__ __forceinline__ u64 pack_key(float d, int v) {
    unsigned u = __float_as_uint(d);
    u ^= ((unsigned)((int)u >> 31)) | 0x80000000u;  // monotonic float->uint
    return ((u64)u << 32) | (unsigned)v;
}

__device__ __forceinline__ float unpack_dist(u64 k) {
    unsigned u = (unsigned)(k >> 32);
    u = (u & 0x80000000u) ? (u ^ 0x80000000u) : ~u;
    return __uint_as_float(u);
}

// ---------------- fused pack (hi-only) + hsq + ht + esq/e2max prep ----------------
// blocks 0..511: pack A (hi) + hsq partials + ht (row-major h_flat, stored IN out0 —
//   dead until k_out overwrites it; k_refine only READS it, k_out runs after);
// 512..767: pack B (hi); 768..831: esq + e2maxp partials (+ out2 zero at 768)
// Apk (halfs): [bm 64][w 8][q 4][r 256][j 8]   window = 8192 halfs
// Bpk (halfs): [bn 32][w 8][q 4][r 128][j 8]   window = 4096 halfs
__global__ __launch_bounds__(256) void k_pack(const float* __restrict__ h,
                                              const float* __restrict__ emb,
                                              _Float16* __restrict__ Apk,
                                              _Float16* __restrict__ Bpk,
                                              float* __restrict__ hsqp,
                                              float* __restrict__ ht,
                                              float* __restrict__ esq,
                                              float* __restrict__ e2maxp,
                                              float* __restrict__ out2) {
    __shared__ float S[8192];
    const int tid = threadIdx.x;
    const int bid = blockIdx.x;
    if (bid < 512) {
        const int bm = bid >> 3, w = bid & 7;
        const int b = bm >> 2, p0 = (bm & 3) * 256;
        const float* src = h + ((size_t)b << 18) + p0;
#pragma unroll 4
        for (int cl = 0; cl < 32; ++cl)
            S[cl * 256 + tid] = src[(size_t)(w * 32 + cl) << 10 | (unsigned)tid];
        __syncthreads();
        // hsq partial for this 32-channel slice, row = tid (exact f32 h values)
        float sq = 0.0f;
#pragma unroll
        for (int cl = 0; cl < 32; ++cl) {
            float t = S[cl * 256 + tid];
            sq = fmaf(t, t, sq);
        }
        hsqp[(size_t)(bm * 8 + w) * 256 + tid] = sq;
        // ht: row-major h_flat slice ht[rg][w*32 .. w*32+31], rg = bm*256 + tid
        float* htr = ht + ((size_t)(bm * 256 + tid)) * D + w * 32;
#pragma unroll
        for (int c4 = 0; c4 < 8; ++c4) {
            float4 t;
            t.x = S[(c4 * 4 + 0) * 256 + tid];
            t.y = S[(c4 * 4 + 1) * 256 + tid];
            t.z = S[(c4 * 4 + 2) * 256 + tid];
            t.w = S[(c4 * 4 + 3) * 256 + tid];
            *(float4*)(htr + c4 * 4) = t;
        }
        _Float16* dstT = Apk + (size_t)bm * 65536 + (size_t)w * 8192;
#pragma unroll
        for (int i = 0; i < 4; ++i) {  // q = i, r = tid
            alignas(16) _Float16 hi[8];
#pragma unroll
            for (int j = 0; j < 8; ++j) hi[j] = (_Float16)S[(i * 8 + j) * 256 + tid];
            *(half8*)(dstT + i * 2048 + tid * 8) = *(half8*)hi;
        }
    } else if (bid < 768) {
        const int bid2 = bid - 512;
        const int bn = bid2 >> 3, w = bid2 & 7;
        const int v0 = bn * 128;
#pragma unroll 4
        for (int i = 0; i < 16; ++i) {
            int flat = i * 256 + tid;
            int r = flat >> 5, cl = flat & 31;
            S[cl * 129 + r] = emb[(size_t)(v0 + r) * D + w * 32 + cl];
        }
        __syncthreads();
        _Float16* dstT = Bpk + (size_t)bn * 32768 + (size_t)w * 4096;
#pragma unroll
        for (int i = 0; i < 2; ++i) {
            int s = i * 256 + tid;
            int q = s >> 7, r = s & 127;
            alignas(16) _Float16 hi[8];
#pragma unroll
            for (int j = 0; j < 8; ++j) hi[j] = (_Float16)S[(q * 8 + j) * 129 + r];
            *(half8*)(dstT + q * 1024 + r * 8) = *(half8*)hi;
        }
    } else {
        // prep: esq + per-64-row e2max partial (was k_prep; fused to save a launch)
        __shared__ float sm[4];
        const int pid = bid - 768;  // 0..63
        const int lane = tid & 63, wv = tid >> 6;
        const int v0 = pid * 64;
        float lmax = 0.0f;
#pragma unroll 4
        for (int i = 0; i < 16; ++i) {
            int v = v0 + i * 4 + wv;
            float4 e = *(const float4*)(emb + (size_t)v * D + lane * 4);
            float s = e.x * e.x + e.y * e.y + e.z * e.z + e.w * e.w;
#pragma unroll
            for (int m = 32; m >= 1; m >>= 1) s += __shfl_xor(s, m, 64);
            if (lane == 0) esq[v] = s;
            lmax = fmaxf(lmax, s);
        }
        if (lane == 0) sm[wv] = lmax;
        __syncthreads();
        if (tid == 0) {
            e2maxp[pid] = fmaxf(fmaxf(sm[0], sm[1]), fmaxf(sm[2], sm[3]));
            if (pid == 0) out2[0] = 0.0f;
        }
    }
}

// ---------------- distance GEMM (single fp16 pass) + per-(row,bn) top-2 ----------------
// Tile 128m x 128n, 256 threads = 4 waves (2m x 2n), wave tile 64x64 = 4x4 frags.
// Triple-buffered LDS (As/Bs 3x8KB = 48KB -> 3 blocks/CU), counted vmcnt(4),
// raw barrier per window. 8 windows of K=32.
// Epilogue (round-8 rework): NO u64 shfl butterfly (that was ~40% of kernel time as
// per-thread VALU + 256 serial bpermutes). Instead: lane-local f32 top-2 over nt
// (v-ascending strict '<' => exact first-index tie-break), pack 2 u64 keys, ds_write
// to t2[row][j16]; then 128 threads (one per row) merge 16 pairs with exact u64
// min-merge (order-insensitive). Two passes (wn=0/1) keep t2 at 32KB in the 48KB smem.

#define STAGE(W, BUF) do { \
    _Pragma("unroll") \
    for (int s_ = 0; s_ < 2; ++s_) { \
        int f_ = s_ * 256 + tid; \
        gld16(AgH + (W) * 8192 + (f_ >> 7) * 2048 + (f_ & 127) * 8, \
              As + (BUF) * 4096 + f_ * 8); \
    } \
    _Pragma("unroll") \
    for (int s_ = 0; s_ < 2; ++s_) { \
        int f_ = s_ * 256 + tid; \
        gld16(Bg + (W) * 4096 + f_ * 8, Bs + (BUF) * 4096 + f_ * 8); \
    } } while (0)

#define PHASE_END(N) do { \
    __builtin_amdgcn_sched_barrier(0); \
    asm volatile("s_waitcnt vmcnt(" #N ")" ::: "memory"); \
    __builtin_amdgcn_s_barrier(); } while (0)

#define WINDOW(BUF, DOSTAGE, SW, SBUF) do { \
    const _Float16* aB = As + (BUF) * 4096 + quad * 1024 + (wm * 64 + j16) * 8; \
    const _Float16* bB = Bs + (BUF) * 4096 + quad * 1024 + (wn * 64 + j16) * 8; \
    if (DOSTAGE) STAGE(SW, SBUF); \
    half8 af[4], bf[4]; \
    _Pragma("unroll") \
    for (int mt_ = 0; mt_ < 4; ++mt_) af[mt_] = *(const half8*)(aB + mt_ * 128); \
    _Pragma("unroll") \
    for (int nt_ = 0; nt_ < 4; ++nt_) bf[nt_] = *(const half8*)(bB + nt_ * 128); \
    __builtin_amdgcn_s_setprio(1); \
    _Pragma("unroll") \
    for (int mt_ = 0; mt_ < 4; ++mt_) { \
      _Pragma("unroll") \
      for (int nt_ = 0; nt_ < 4; ++nt_) \
        acc[mt_][nt_] = __builtin_amdgcn_mfma_f32_16x16x32_f16(af[mt_], bf[nt_], acc[mt_][nt_], 0, 0, 0); \
    } \
    __builtin_amdgcn_s_setprio(0); \
  } while (0)

__global__ __launch_bounds__(256, 3) void k_gemm(const _Float16* __restrict__ Apk,
                                                 const _Float16* __restrict__ Bpk,
                                                 const float* __restrict__ esq,
                                                 u64* __restrict__ keys2) {
    __shared__ alignas(16) char smem[49152];  // K-loop: As 24KB | Bs 24KB; epi: t2 32KB
    _Float16* As = (_Float16*)smem;           // 3 x [q 4][r 128][j 8] = 24KB
    _Float16* Bs = (_Float16*)(smem + 24576); // 3 x [q 4][r 128][j 8] = 24KB

    const int tid = threadIdx.x;
    const int bid = blockIdx.x;
    // XCD-chunked bijective swizzle (4096 % 8 == 0); bn fastest for A-panel L2 reuse
    const int swz = (bid & 7) * 512 + (bid >> 3);
    const int bm = swz >> 5, bn = swz & 31;
    const int m0 = bm * 128, n0 = bn * 128;

    // Apk panels are 256 rows: this block takes half (bm&1) of panel bm>>1
    const _Float16* AgH = Apk + (size_t)(bm >> 1) * 65536 + (size_t)(bm & 1) * 1024;
    const _Float16* Bg = Bpk + (size_t)bn * 32768;

    STAGE(0, 0);
    STAGE(1, 1);

    const int wv = tid >> 6, l = tid & 63;
    const int wm = wv & 1, wn = wv >> 1;
    const int quad = l >> 4, j16 = l & 15;

    f32x4 acc[4][4];
#pragma unroll
    for (int i = 0; i < 4; ++i)
#pragma unroll
        for (int j = 0; j < 4; ++j) acc[i][j] = (f32x4)0.0f;

    asm volatile("s_waitcnt vmcnt(4)" ::: "memory");  // window 0 landed; w1 in flight
    __builtin_amdgcn_s_barrier();

    WINDOW(0, 1, 2, 2); PHASE_END(4);   // w0; stage w2; wait: w1 ready
    WINDOW(1, 1, 3, 0); PHASE_END(4);   // w1; stage w3; wait: w2 ready
    WINDOW(2, 1, 4, 1); PHASE_END(4);
    WINDOW(0, 1, 5, 2); PHASE_END(4);
    WINDOW(1, 1, 6, 0); PHASE_END(4);
    WINDOW(2, 1, 7, 1); PHASE_END(4);
    WINDOW(0, 0, 0, 0); PHASE_END(0);   // w6; wait: w7 ready
    WINDOW(1, 0, 0, 0);                 // w7
    __syncthreads();                    // all MFMA reads done; smem reusable

    // ---- epilogue: per-(row, bn) top-2 via LDS transpose (no shfl butterfly) ----
    u64* t2 = (u64*)smem;  // [128 rows][16 j (xor row&7)][2 slots] = 32KB
    float es[4];
    int vidx[4];
#pragma unroll
    for (int nt = 0; nt < 4; ++nt) {
        vidx[nt] = n0 + wn * 64 + nt * 16 + j16;
        es[nt] = esq[vidx[nt]];
    }

    u64 M1 = ~0ULL, M2 = ~0ULL;  // phase-B accumulators (tid < 128)
#pragma unroll
    for (int pass = 0; pass < 2; ++pass) {
        if (wn == pass) {
#pragma unroll
            for (int mt = 0; mt < 4; ++mt) {
#pragma unroll
                for (int r = 0; r < 4; ++r) {
                    float d1 = __builtin_inff(), d2 = __builtin_inff();
                    int i1 = 0, i2 = 0;
#pragma unroll
                    for (int nt = 0; nt < 4; ++nt) {
                        float dv = es[nt] - 2.0f * acc[mt][nt][r];
                        bool c1 = dv < d1;
                        bool c2 = dv < d2;
                        d2 = c1 ? d1 : (c2 ? dv : d2);
                        i2 = c1 ? i1 : (c2 ? vidx[nt] : i2);
                        d1 = c1 ? dv : d1;
                        i1 = c1 ? vidx[nt] : i1;
                    }
                    int row = wm * 64 + mt * 16 + quad * 4 + r;
                    u64* p = t2 + ((size_t)(row * 16 + (j16 ^ (row & 7))) * 2);
                    p[0] = pack_key(d1, i1);
                    p[1] = pack_key(d2, i2);
                }
            }
        }
        __syncthreads();
        if (tid < 128) {
            const int row = tid;
#pragma unroll
            for (int j = 0; j < 16; ++j) {
                const u64* p = t2 + ((size_t)(row * 16 + (j ^ (row & 7))) * 2);
                u64 a1 = p[0], a2 = p[1];
                u64 x = M1 > a1 ? M1 : a1;   // max(M1, a1)
                M1 = M1 < a1 ? M1 : a1;      // min
                u64 y = M2 < a2 ? M2 : a2;   // min(M2, a2)
                M2 = x < y ? x : y;          // 2nd smallest overall
            }
        }
        __syncthreads();
    }
    if (tid < 128) {
        // row-major: keys2[row][bn][slot]
        keys2[(size_t)(m0 + tid) * 64 + bn * 2 + 0] = M1;
        keys2[(size_t)(m0 + tid) * 64 + bn * 2 + 1] = M2;
    }
}

// ---------------- refine: windowed exact argmin -> out1 (READS out0-as-ht only) ----------------
__device__ __forceinline__ u64 exact_key_ht(const float* __restrict__ ht,
                                            const float* __restrict__ emb,
                                            const float* __restrict__ esq,
                                            int rg, int v, int lane) {
    const float4 h4 = *(const float4*)(ht + (size_t)rg * D + lane * 4);
    const float4 e4 = *(const float4*)(emb + (size_t)v * D + lane * 4);
    float p = h4.x * e4.x;
    p = fmaf(h4.y, e4.y, p);
    p = fmaf(h4.z, e4.z, p);
    p = fmaf(h4.w, e4.w, p);
#pragma unroll
    for (int m = 32; m >= 1; m >>= 1) p += __shfl_xor(p, m, 64);
    return pack_key(esq[v] - 2.0f * p, v);
}

__global__ __launch_bounds__(256) void k_refine(const float* __restrict__ ht,  // = out0
                                                const float* __restrict__ emb,
                                                const float* __restrict__ esq,
                                                const float* __restrict__ hsqp,
                                                const float* __restrict__ e2maxp,
                                                const u64* __restrict__ keys2,
                                                float* __restrict__ out1) {
    __shared__ float sE2;
    const int tid = threadIdx.x;
    const int lane = tid & 63;
    const int w = tid >> 6;
    const int n0 = blockIdx.x * 32;

    // E2max from the 64 partials (replaces the old single-block reduce kernel)
    if (tid < 64) {
        float m = e2maxp[tid];
#pragma unroll
        for (int s = 32; s >= 1; s >>= 1) m = fmaxf(m, __shfl_xor(m, s, 64));
        if (tid == 0) sE2 = m;
    }
    __syncthreads();
    const float e2m = sE2;

    // wave w owns rows w*8 .. w*8+7; prefetch next row's keys under current reduce
    int rg = n0 + w * 8;
    u64 key = keys2[(size_t)rg * 64 + lane];
#pragma unroll 1
    for (int rr = 0; rr < 8; ++rr, ++rg) {
        u64 keyn = 0;
        if (rr < 7) keyn = keys2[(size_t)(rg + 1) * 64 + lane];
        u64 gm = key;
#pragma unroll
        for (int m = 32; m >= 1; m >>= 1) {
            u64 o = __shfl_xor(gm, m, 64);
            gm = o < gm ? o : gm;
        }
        // sound error window: |approx - true| <= B = 2^-9*||h||*||e||max; thr = gm+2B+slack
        float hq = 0.0f;
#pragma unroll
        for (int k = 0; k < 8; ++k) hq += hsqp[(size_t)(rg >> 8) * 2048 + k * 256 + (rg & 255)];
        const float thr = unpack_dist(gm) + 4.0e-3f * sqrtf(hq * e2m) + 1e-2f;
        u64 cmask = __ballot(unpack_dist(key) <= thr);
        u64 bestk;
        if (__popcll(cmask) == 1) {
            // fast path: only gmin is in-window among stored keys; every block's
            // unstored (rank>=3) keys >= its stored slot-1 key > thr => gmin exact.
            bestk = gm;
        } else {
            bestk = ~0ULL;
            u64 rescan = 0;  // bn set whose slot-1 is in-window (rank>=3 unknown)
            u64 cm = cmask;
            while (cm) {
                int L = __ffsll((long long)cm) - 1;
                cm &= cm - 1;
                if (L & 1) {
                    rescan |= 1ull << (L >> 1);
                } else {
                    u64 kL = __shfl(key, L, 64);
                    u64 ek = exact_key_ht(ht, emb, esq, rg, (int)(kL & 0xFFFFFFFFu), lane);
                    bestk = ek < bestk ? ek : bestk;
                }
            }
            // rare path, LANE-PARALLEL: 64 lanes x 2 candidates, serial f32 dot,
            // top-2 wave reduce, exact re-eval of the 2 survivors (shared rounding).
            while (rescan) {
                int bnr = __ffsll((long long)rescan) - 1;
                rescan &= rescan - 1;
                const float* htr = ht + (size_t)rg * D;
                u64 k0 = ~0ULL, k1 = ~0ULL;
#pragma unroll
                for (int c = 0; c < 2; ++c) {
                    int v = bnr * 128 + c * 64 + lane;
                    float p = 0.0f;
#pragma unroll 8
                    for (int d = 0; d < D; d += 4) {
                        float4 hh = *(const float4*)(htr + d);
                        float4 ee = *(const float4*)(emb + (size_t)v * D + d);
                        p = fmaf(hh.x, ee.x, p);
                        p = fmaf(hh.y, ee.y, p);
                        p = fmaf(hh.z, ee.z, p);
                        p = fmaf(hh.w, ee.w, p);
                    }
                    u64 kc = pack_key(esq[v] - 2.0f * p, v);
                    if (c == 0) k0 = kc; else k1 = kc;
                }
                u64 m1 = k0 < k1 ? k0 : k1, m2 = k0 < k1 ? k1 : k0;
#pragma unroll
                for (int m = 32; m >= 1; m >>= 1) {
                    u64 o1 = __shfl_xor(m1, m, 64), o2 = __shfl_xor(m2, m, 64);
                    u64 hi = m1 > o1 ? m1 : o1;
                    m1 = m1 < o1 ? m1 : o1;
                    u64 lo2 = m2 < o2 ? m2 : o2;
                    m2 = hi < lo2 ? hi : lo2;
                }
                u64 e1 = exact_key_ht(ht, emb, esq, rg, (int)(m1 & 0xFFFFFFFFu), lane);
                u64 e2 = exact_key_ht(ht, emb, esq, rg, (int)(m2 & 0xFFFFFFFFu), lane);
                bestk = e1 < bestk ? e1 : bestk;
                bestk = e2 < bestk ? e2 : bestk;
            }
        }
        if (lane == 0) out1[rg] = (float)(int)(bestk & 0xFFFFFFFFu);
        key = keyn;
    }
}

// ---------------- out: gather emb by index, write z_q_st (overwrites ht) + loss ----------------
// Separate launch AFTER k_refine: kernel boundary guarantees every block's ht reads
// finished before any out0 overwrite.
__global__ __launch_bounds__(256) void k_out(const float* __restrict__ h,
                                             const float* __restrict__ emb,
                                             const float* __restrict__ out1,
                                             float* __restrict__ out0,
                                             float* __restrict__ out2) {
    __shared__ float zq[32][260];
    __shared__ float wred[4];
    const int tid = threadIdx.x;
    const int lane = tid & 63;
    const int w = tid >> 6;
    const int n0 = blockIdx.x * 32;
    const int b = n0 >> 10;
    const int p0 = n0 & 1023;
#pragma unroll
    for (int rr = 0; rr < 8; ++rr) {
        int r = w * 8 + rr;
        unsigned idx = (unsigned)(int)out1[n0 + r];
        float4 e4 = *(const float4*)(emb + (size_t)idx * D + lane * 4);
        *(float4*)&zq[r][lane * 4] = e4;
    }
    __syncthreads();
    float lsum = 0.0f;
    const size_t base = ((size_t)b * D) << 10;
#pragma unroll 4
    for (int it = 0; it < 32; ++it) {
        int c = it * 8 + (tid >> 5);
        int pp = tid & 31;
        float z = zq[pp][c];
        size_t g = base + ((size_t)c << 10) + p0 + pp;
        float hv = h[g];
        out0[g] = hv + (z - hv);
        float d = hv - z;
        lsum = fmaf(d, d, lsum);
    }
#pragma unroll
    for (int m = 32; m >= 1; m >>= 1) lsum += __shfl_xor(lsum, m, 64);
    if (lane == 0) wred[w] = lsum;
    __syncthreads();
    if (tid == 0)
        atomicAdd(out2, (wred[0] + wred[1] + wred[2] + wred[3]) * (1.0f / (float)N_OUT0));
}

extern "C" void kernel_launch(void* const* d_in, const int* in_sizes, int n_in,
                              void* d_out, int out_size, void* d_ws, size_t ws_size,
                              hipStream_t stream) {
    const float* h = (const float*)d_in[0];
    const float* emb = (const float*)d_in[1];
    float* out0 = (float*)d_out;
    float* out1 = out0 + N_OUT0;
    float* out2 = out1 + NTOT;

    // ws: Apk 8MB | Bpk 2MB | esq 16KB | hsqp 512KB | e2maxp 1KB | (pad) | keys2 8MB
    //     total ~18.5MB (ws >= 21.1MB confirmed). ht (16MB) lives in out0 until k_out.
    char* wsb = (char*)d_ws;
    _Float16* Apk = (_Float16*)wsb;
    _Float16* Bpk = (_Float16*)(wsb + 8388608);
    float* esq = (float*)(wsb + 10485760);
    float* hsqp = (float*)(wsb + 10502144);
    float* e2maxp = (float*)(wsb + 11026432);
    u64* keys2 = (u64*)(wsb + 11028480);

    hipLaunchKernelGGL(k_pack, dim3(832), dim3(256), 0, stream, h, emb, Apk, Bpk, hsqp, out0, esq, e2maxp, out2);
    hipLaunchKernelGGL(k_gemm, dim3(4096), dim3(256), 0, stream, Apk, Bpk, esq, keys2);
    hipLaunchKernelGGL(k_refine, dim3(NTOT / 32), dim3(256), 0, stream, out0, emb, esq, hsqp, e2maxp, keys2, out1);
    hipLaunchKernelGGL(k_out, dim3(NTOT / 32), dim3(256), 0, stream, h, emb, out1, out0, out2);
}

// Round 10
// 181.312 us; speedup vs baseline: 1.6904x; 1.0481x over previous
//
#include <hip/hip_runtime.h>

#define D 256
#define VOCAB 4096
#define NTOT 16384      // 16 * 32 * 32
#define N_OUT0 4194304  // 16*256*32*32

typedef _Float16 half8 __attribute__((ext_vector_type(8)));
typedef float f32x4 __attribute__((ext_vector_type(4)));
typedef unsigned long long u64;

__device__ __forceinline__ u64 pack_key(float d, int v) {
    unsigned u = __float_as_uint(d);
    u ^= ((unsigned)((int)u >> 31)) | 0x80000000u;  // monotonic float->uint
    return ((u64)u << 32) | (unsigned)v;
}

__device__ __forceinline__ float unpack_dist(u64 k) {
    unsigned u = (unsigned)(k >> 32);
    u = (u & 0x80000000u) ? (u ^ 0x80000000u) : ~u;
    return __uint_as_float(u);
}

// ---------------- fused pack (hi-only) + hsq + ht + esq/e2max prep ----------------
// blocks 0..511: pack A (hi) + hsq partials + ht (row-major h_flat, stored IN out0 —
//   dead until k_out overwrites it; k_refine only READS it, k_out runs after);
// 512..767: pack B (hi); 768..831: esq + e2maxp partials (+ out2 zero at 768)
// Apk (halfs): [bm 64][w 8][q 4][r 256][j 8]   window = 8192 halfs
// Bpk (halfs): [bn 32][w 8][q 4][r 128][j 8]   window = 4096 halfs
__global__ __launch_bounds__(256) void k_pack(const float* __restrict__ h,
                                              const float* __restrict__ emb,
                                              _Float16* __restrict__ Apk,
                                              _Float16* __restrict__ Bpk,
                                              float* __restrict__ hsqp,
                                              float* __restrict__ ht,
                                              float* __restrict__ esq,
                                              float* __restrict__ e2maxp,
                                              float* __restrict__ out2) {
    __shared__ float S[8192];
    const int tid = threadIdx.x;
    const int bid = blockIdx.x;
    if (bid < 512) {
        const int bm = bid >> 3, w = bid & 7;
        const int b = bm >> 2, p0 = (bm & 3) * 256;
        const float* src = h + ((size_t)b << 18) + p0;
#pragma unroll 4
        for (int cl = 0; cl < 32; ++cl)
            S[cl * 256 + tid] = src[(size_t)(w * 32 + cl) << 10 | (unsigned)tid];
        __syncthreads();
        // hsq partial for this 32-channel slice, row = tid (exact f32 h values)
        float sq = 0.0f;
#pragma unroll
        for (int cl = 0; cl < 32; ++cl) {
            float t = S[cl * 256 + tid];
            sq = fmaf(t, t, sq);
        }
        hsqp[(size_t)(bm * 8 + w) * 256 + tid] = sq;
        // ht: row-major h_flat slice ht[rg][w*32 .. w*32+31], rg = bm*256 + tid
        float* htr = ht + ((size_t)(bm * 256 + tid)) * D + w * 32;
#pragma unroll
        for (int c4 = 0; c4 < 8; ++c4) {
            float4 t;
            t.x = S[(c4 * 4 + 0) * 256 + tid];
            t.y = S[(c4 * 4 + 1) * 256 + tid];
            t.z = S[(c4 * 4 + 2) * 256 + tid];
            t.w = S[(c4 * 4 + 3) * 256 + tid];
            *(float4*)(htr + c4 * 4) = t;
        }
        _Float16* dstT = Apk + (size_t)bm * 65536 + (size_t)w * 8192;
#pragma unroll
        for (int i = 0; i < 4; ++i) {  // q = i, r = tid
            alignas(16) _Float16 hi[8];
#pragma unroll
            for (int j = 0; j < 8; ++j) hi[j] = (_Float16)S[(i * 8 + j) * 256 + tid];
            *(half8*)(dstT + i * 2048 + tid * 8) = *(half8*)hi;
        }
    } else if (bid < 768) {
        const int bid2 = bid - 512;
        const int bn = bid2 >> 3, w = bid2 & 7;
        const int v0 = bn * 128;
#pragma unroll 4
        for (int i = 0; i < 16; ++i) {
            int flat = i * 256 + tid;
            int r = flat >> 5, cl = flat & 31;
            S[cl * 129 + r] = emb[(size_t)(v0 + r) * D + w * 32 + cl];
        }
        __syncthreads();
        _Float16* dstT = Bpk + (size_t)bn * 32768 + (size_t)w * 4096;
#pragma unroll
        for (int i = 0; i < 2; ++i) {
            int s = i * 256 + tid;
            int q = s >> 7, r = s & 127;
            alignas(16) _Float16 hi[8];
#pragma unroll
            for (int j = 0; j < 8; ++j) hi[j] = (_Float16)S[(q * 8 + j) * 129 + r];
            *(half8*)(dstT + q * 1024 + r * 8) = *(half8*)hi;
        }
    } else {
        // prep: esq + per-64-row e2max partial
        __shared__ float sm[4];
        const int pid = bid - 768;  // 0..63
        const int lane = tid & 63, wv = tid >> 6;
        const int v0 = pid * 64;
        float lmax = 0.0f;
#pragma unroll 4
        for (int i = 0; i < 16; ++i) {
            int v = v0 + i * 4 + wv;
            float4 e = *(const float4*)(emb + (size_t)v * D + lane * 4);
            float s = e.x * e.x + e.y * e.y + e.z * e.z + e.w * e.w;
#pragma unroll
            for (int m = 32; m >= 1; m >>= 1) s += __shfl_xor(s, m, 64);
            if (lane == 0) esq[v] = s;
            lmax = fmaxf(lmax, s);
        }
        if (lane == 0) sm[wv] = lmax;
        __syncthreads();
        if (tid == 0) {
            e2maxp[pid] = fmaxf(fmaxf(sm[0], sm[1]), fmaxf(sm[2], sm[3]));
            if (pid == 0) out2[0] = 0.0f;
        }
    }
}

// ---------------- distance GEMM (single fp16 pass, LDS-FREE K-loop) + top-2 ----------------
// Round-10 rework: the K-loop was LDS-read-bound (32KB LDS reads per 16KB staged per
// window; ~385 cyc/window vs 78 cyc MFMA). Apk/Bpk are stored in exact MFMA fragment
// order and are L2-resident per-XCD (1MB A-panels + 2MB B < 4MB/XCD under the swizzle),
// so fragments are loaded DIRECTLY global->VGPR: 4 A + 4 B x 16B per window per lane,
// coalesced 1KB/instruction. No staging, no K-loop barriers. One-window register
// prefetch (named arrays + full unroll -> static indices) hides L2 latency (~200cyc).
// LDS keeps only the 32KB t2 epilogue. Same fragments, same MFMA order as round 9 ->
// bitwise-identical accumulators.
__global__ __launch_bounds__(256, 3) void k_gemm(const _Float16* __restrict__ Apk,
                                                 const _Float16* __restrict__ Bpk,
                                                 const float* __restrict__ esq,
                                                 u64* __restrict__ keys2) {
    __shared__ u64 t2[4096];  // [128 rows][16 j (xor row&7)][2 slots] = 32KB (t2[0..4095])

    const int tid = threadIdx.x;
    const int bid = blockIdx.x;
    // XCD-chunked bijective swizzle (4096 % 8 == 0); bn fastest for A-panel L2 reuse
    const int swz = (bid & 7) * 512 + (bid >> 3);
    const int bm = swz >> 5, bn = swz & 31;
    const int m0 = bm * 128, n0 = bn * 128;

    const int wv = tid >> 6, l = tid & 63;
    const int wm = wv & 1, wn = wv >> 1;
    const int quad = l >> 4, j16 = l & 15;

    // per-lane fragment base pointers (Apk panels are 256 rows: half (bm&1) of panel bm>>1)
    const _Float16* aP = Apk + (size_t)(bm >> 1) * 65536 + (size_t)(bm & 1) * 1024
                       + quad * 2048 + (wm * 64 + j16) * 8;
    const _Float16* bP = Bpk + (size_t)bn * 32768
                       + quad * 1024 + (wn * 64 + j16) * 8;

    f32x4 acc[4][4];
#pragma unroll
    for (int i = 0; i < 4; ++i)
#pragma unroll
        for (int j = 0; j < 4; ++j) acc[i][j] = (f32x4)0.0f;

    half8 af[4], bf[4], afn[4], bfn[4];
#pragma unroll
    for (int mt = 0; mt < 4; ++mt) af[mt] = *(const half8*)(aP + mt * 128);
#pragma unroll
    for (int nt = 0; nt < 4; ++nt) bf[nt] = *(const half8*)(bP + nt * 128);

#pragma unroll
    for (int w = 0; w < 8; ++w) {
        if (w < 7) {  // prefetch next window's fragments (issues before MFMAs below)
#pragma unroll
            for (int mt = 0; mt < 4; ++mt)
                afn[mt] = *(const half8*)(aP + (w + 1) * 8192 + mt * 128);
#pragma unroll
            for (int nt = 0; nt < 4; ++nt)
                bfn[nt] = *(const half8*)(bP + (w + 1) * 4096 + nt * 128);
        }
        __builtin_amdgcn_s_setprio(1);
#pragma unroll
        for (int mt = 0; mt < 4; ++mt)
#pragma unroll
            for (int nt = 0; nt < 4; ++nt)
                acc[mt][nt] = __builtin_amdgcn_mfma_f32_16x16x32_f16(af[mt], bf[nt], acc[mt][nt], 0, 0, 0);
        __builtin_amdgcn_s_setprio(0);
#pragma unroll
        for (int mt = 0; mt < 4; ++mt) af[mt] = afn[mt];
#pragma unroll
        for (int nt = 0; nt < 4; ++nt) bf[nt] = bfn[nt];
    }

    // ---- epilogue: per-(row, bn) top-2 via LDS transpose (proven in round 9) ----
    float es[4];
    int vidx[4];
#pragma unroll
    for (int nt = 0; nt < 4; ++nt) {
        vidx[nt] = n0 + wn * 64 + nt * 16 + j16;
        es[nt] = esq[vidx[nt]];
    }

    u64 M1 = ~0ULL, M2 = ~0ULL;  // phase-B accumulators (tid < 128)
#pragma unroll
    for (int pass = 0; pass < 2; ++pass) {
        if (wn == pass) {
#pragma unroll
            for (int mt = 0; mt < 4; ++mt) {
#pragma unroll
                for (int r = 0; r < 4; ++r) {
                    float d1 = __builtin_inff(), d2 = __builtin_inff();
                    int i1 = 0, i2 = 0;
#pragma unroll
                    for (int nt = 0; nt < 4; ++nt) {
                        float dv = es[nt] - 2.0f * acc[mt][nt][r];
                        bool c1 = dv < d1;
                        bool c2 = dv < d2;
                        d2 = c1 ? d1 : (c2 ? dv : d2);
                        i2 = c1 ? i1 : (c2 ? vidx[nt] : i2);
                        d1 = c1 ? dv : d1;
                        i1 = c1 ? vidx[nt] : i1;
                    }
                    int row = wm * 64 + mt * 16 + quad * 4 + r;
                    u64* p = t2 + ((size_t)(row * 16 + (j16 ^ (row & 7))) * 2);
                    p[0] = pack_key(d1, i1);
                    p[1] = pack_key(d2, i2);
                }
            }
        }
        __syncthreads();
        if (tid < 128) {
            const int row = tid;
#pragma unroll
            for (int j = 0; j < 16; ++j) {
                const u64* p = t2 + ((size_t)(row * 16 + (j ^ (row & 7))) * 2);
                u64 a1 = p[0], a2 = p[1];
                u64 x = M1 > a1 ? M1 : a1;   // max(M1, a1)
                M1 = M1 < a1 ? M1 : a1;      // min
                u64 y = M2 < a2 ? M2 : a2;   // min(M2, a2)
                M2 = x < y ? x : y;          // 2nd smallest overall
            }
        }
        __syncthreads();
    }
    if (tid < 128) {
        // row-major: keys2[row][bn][slot]
        keys2[(size_t)(m0 + tid) * 64 + bn * 2 + 0] = M1;
        keys2[(size_t)(m0 + tid) * 64 + bn * 2 + 1] = M2;
    }
}

// ---------------- refine: windowed exact argmin -> out1 (READS out0-as-ht only) ----------------
__device__ __forceinline__ u64 exact_key_ht(const float* __restrict__ ht,
                                            const float* __restrict__ emb,
                                            const float* __restrict__ esq,
                                            int rg, int v, int lane) {
    const float4 h4 = *(const float4*)(ht + (size_t)rg * D + lane * 4);
    const float4 e4 = *(const float4*)(emb + (size_t)v * D + lane * 4);
    float p = h4.x * e4.x;
    p = fmaf(h4.y, e4.y, p);
    p = fmaf(h4.z, e4.z, p);
    p = fmaf(h4.w, e4.w, p);
#pragma unroll
    for (int m = 32; m >= 1; m >>= 1) p += __shfl_xor(p, m, 64);
    return pack_key(esq[v] - 2.0f * p, v);
}

__global__ __launch_bounds__(256) void k_refine(const float* __restrict__ ht,  // = out0
                                                const float* __restrict__ emb,
                                                const float* __restrict__ esq,
                                                const float* __restrict__ hsqp,
                                                const float* __restrict__ e2maxp,
                                                const u64* __restrict__ keys2,
                                                float* __restrict__ out1) {
    __shared__ float sE2;
    const int tid = threadIdx.x;
    const int lane = tid & 63;
    const int w = tid >> 6;
    const int n0 = blockIdx.x * 32;

    // E2max from the 64 partials
    if (tid < 64) {
        float m = e2maxp[tid];
#pragma unroll
        for (int s = 32; s >= 1; s >>= 1) m = fmaxf(m, __shfl_xor(m, s, 64));
        if (tid == 0) sE2 = m;
    }
    __syncthreads();
    const float e2m = sE2;

    // wave w owns rows w*8 .. w*8+7; prefetch next row's keys under current reduce
    int rg = n0 + w * 8;
    u64 key = keys2[(size_t)rg * 64 + lane];
#pragma unroll 1
    for (int rr = 0; rr < 8; ++rr, ++rg) {
        u64 keyn = 0;
        if (rr < 7) keyn = keys2[(size_t)(rg + 1) * 64 + lane];
        u64 gm = key;
#pragma unroll
        for (int m = 32; m >= 1; m >>= 1) {
            u64 o = __shfl_xor(gm, m, 64);
            gm = o < gm ? o : gm;
        }
        // sound error window: |approx - true| <= B = 2^-9*||h||*||e||max; thr = gm+2B+slack
        float hq = 0.0f;
#pragma unroll
        for (int k = 0; k < 8; ++k) hq += hsqp[(size_t)(rg >> 8) * 2048 + k * 256 + (rg & 255)];
        const float thr = unpack_dist(gm) + 4.0e-3f * sqrtf(hq * e2m) + 1e-2f;
        u64 cmask = __ballot(unpack_dist(key) <= thr);
        u64 bestk;
        if (__popcll(cmask) == 1) {
            // fast path: only gmin is in-window among stored keys; every block's
            // unstored (rank>=3) keys >= its stored slot-1 key > thr => gmin exact.
            bestk = gm;
        } else {
            bestk = ~0ULL;
            u64 rescan = 0;  // bn set whose slot-1 is in-window (rank>=3 unknown)
            u64 cm = cmask;
            while (cm) {
                int L = __ffsll((long long)cm) - 1;
                cm &= cm - 1;
                if (L & 1) {
                    rescan |= 1ull << (L >> 1);
                } else {
                    u64 kL = __shfl(key, L, 64);
                    u64 ek = exact_key_ht(ht, emb, esq, rg, (int)(kL & 0xFFFFFFFFu), lane);
                    bestk = ek < bestk ? ek : bestk;
                }
            }
            // rare path, LANE-PARALLEL: 64 lanes x 2 candidates, serial f32 dot,
            // top-2 wave reduce, exact re-eval of the 2 survivors (shared rounding).
            while (rescan) {
                int bnr = __ffsll((long long)rescan) - 1;
                rescan &= rescan - 1;
                const float* htr = ht + (size_t)rg * D;
                u64 k0 = ~0ULL, k1 = ~0ULL;
#pragma unroll
                for (int c = 0; c < 2; ++c) {
                    int v = bnr * 128 + c * 64 + lane;
                    float p = 0.0f;
#pragma unroll 8
                    for (int d = 0; d < D; d += 4) {
                        float4 hh = *(const float4*)(htr + d);
                        float4 ee = *(const float4*)(emb + (size_t)v * D + d);
                        p = fmaf(hh.x, ee.x, p);
                        p = fmaf(hh.y, ee.y, p);
                        p = fmaf(hh.z, ee.z, p);
                        p = fmaf(hh.w, ee.w, p);
                    }
                    u64 kc = pack_key(esq[v] - 2.0f * p, v);
                    if (c == 0) k0 = kc; else k1 = kc;
                }
                u64 m1 = k0 < k1 ? k0 : k1, m2 = k0 < k1 ? k1 : k0;
#pragma unroll
                for (int m = 32; m >= 1; m >>= 1) {
                    u64 o1 = __shfl_xor(m1, m, 64), o2 = __shfl_xor(m2, m, 64);
                    u64 hi = m1 > o1 ? m1 : o1;
                    m1 = m1 < o1 ? m1 : o1;
                    u64 lo2 = m2 < o2 ? m2 : o2;
                    m2 = hi < lo2 ? hi : lo2;
                }
                u64 e1 = exact_key_ht(ht, emb, esq, rg, (int)(m1 & 0xFFFFFFFFu), lane);
                u64 e2 = exact_key_ht(ht, emb, esq, rg, (int)(m2 & 0xFFFFFFFFu), lane);
                bestk = e1 < bestk ? e1 : bestk;
                bestk = e2 < bestk ? e2 : bestk;
            }
        }
        if (lane == 0) out1[rg] = (float)(int)(bestk & 0xFFFFFFFFu);
        key = keyn;
    }
}

// ---------------- out: gather emb by index, write z_q_st (overwrites ht) + loss ----------------
__global__ __launch_bounds__(256) void k_out(const float* __restrict__ h,
                                             const float* __restrict__ emb,
                                             const float* __restrict__ out1,
                                             float* __restrict__ out0,
                                             float* __restrict__ out2) {
    __shared__ float zq[32][260];
    __shared__ float wred[4];
    const int tid = threadIdx.x;
    const int lane = tid & 63;
    const int w = tid >> 6;
    const int n0 = blockIdx.x * 32;
    const int b = n0 >> 10;
    const int p0 = n0 & 1023;
#pragma unroll
    for (int rr = 0; rr < 8; ++rr) {
        int r = w * 8 + rr;
        unsigned idx = (unsigned)(int)out1[n0 + r];
        float4 e4 = *(const float4*)(emb + (size_t)idx * D + lane * 4);
        *(float4*)&zq[r][lane * 4] = e4;
    }
    __syncthreads();
    float lsum = 0.0f;
    const size_t base = ((size_t)b * D) << 10;
#pragma unroll 4
    for (int it = 0; it < 32; ++it) {
        int c = it * 8 + (tid >> 5);
        int pp = tid & 31;
        float z = zq[pp][c];
        size_t g = base + ((size_t)c << 10) + p0 + pp;
        float hv = h[g];
        out0[g] = hv + (z - hv);
        float d = hv - z;
        lsum = fmaf(d, d, lsum);
    }
#pragma unroll
    for (int m = 32; m >= 1; m >>= 1) lsum += __shfl_xor(lsum, m, 64);
    if (lane == 0) wred[w] = lsum;
    __syncthreads();
    if (tid == 0)
        atomicAdd(out2, (wred[0] + wred[1] + wred[2] + wred[3]) * (1.0f / (float)N_OUT0));
}

extern "C" void kernel_launch(void* const* d_in, const int* in_sizes, int n_in,
                              void* d_out, int out_size, void* d_ws, size_t ws_size,
                              hipStream_t stream) {
    const float* h = (const float*)d_in[0];
    const float* emb = (const float*)d_in[1];
    float* out0 = (float*)d_out;
    float* out1 = out0 + N_OUT0;
    float* out2 = out1 + NTOT;

    // ws: Apk 8MB | Bpk 2MB | esq 16KB | hsqp 512KB | e2maxp 1KB | (pad) | keys2 8MB
    //     total ~18.5MB (ws >= 21.1MB confirmed). ht (16MB) lives in out0 until k_out.
    char* wsb = (char*)d_ws;
    _Float16* Apk = (_Float16*)wsb;
    _Float16* Bpk = (_Float16*)(wsb + 8388608);
    float* esq = (float*)(wsb + 10485760);
    float* hsqp = (float*)(wsb + 10502144);
    float* e2maxp = (float*)(wsb + 11026432);
    u64* keys2 = (u64*)(wsb + 11028480);

    hipLaunchKernelGGL(k_pack, dim3(832), dim3(256), 0, stream, h, emb, Apk, Bpk, hsqp, out0, esq, e2maxp, out2);
    hipLaunchKernelGGL(k_gemm, dim3(4096), dim3(256), 0, stream, Apk, Bpk, esq, keys2);
    hipLaunchKernelGGL(k_refine, dim3(NTOT / 32), dim3(256), 0, stream, out0, emb, esq, hsqp, e2maxp, keys2, out1);
    hipLaunchKernelGGL(k_out, dim3(NTOT / 32), dim3(256), 0, stream, h, emb, out1, out0, out2);
}

// Round 12
// 170.254 us; speedup vs baseline: 1.8002x; 1.0650x over previous
//
#include <hip/hip_runtime.h>

#define D 256
#define VOCAB 4096
#define NTOT 16384      // 16 * 32 * 32
#define N_OUT0 4194304  // 16*256*32*32

typedef _Float16 half8 __attribute__((ext_vector_type(8)));
typedef float f32x4 __attribute__((ext_vector_type(4)));
typedef unsigned long long u64;

__device__ __forceinline__ u64 pack_key(float d, int v) {
    unsigned u = __float_as_uint(d);
    u ^= ((unsigned)((int)u >> 31)) | 0x80000000u;  // monotonic float->uint
    return ((u64)u << 32) | (unsigned)v;
}

// ---------------- fused pack (hi-only) + hsq + ht + esq/e2max prep ----------------
// ROUND-10 VERBATIM (proven post-timing-stable).
// blocks 0..511: pack A (hi) + hsq partials + ht (row-major h_flat, stored IN out0 —
//   dead until k_out overwrites it; k_refine only READS it, k_out runs after);
// 512..767: pack B (hi); 768..831: esq + e2maxp partials (+ out2 zero at 768)
__global__ __launch_bounds__(256) void k_pack(const float* __restrict__ h,
                                              const float* __restrict__ emb,
                                              _Float16* __restrict__ Apk,
                                              _Float16* __restrict__ Bpk,
                                              float* __restrict__ hsqp,
                                              float* __restrict__ ht,
                                              float* __restrict__ esq,
                                              float* __restrict__ e2maxp,
                                              float* __restrict__ out2) {
    __shared__ float S[8192];
    const int tid = threadIdx.x;
    const int bid = blockIdx.x;
    if (bid < 512) {
        const int bm = bid >> 3, w = bid & 7;
        const int b = bm >> 2, p0 = (bm & 3) * 256;
        const float* src = h + ((size_t)b << 18) + p0;
#pragma unroll 4
        for (int cl = 0; cl < 32; ++cl)
            S[cl * 256 + tid] = src[(size_t)(w * 32 + cl) << 10 | (unsigned)tid];
        __syncthreads();
        float sq = 0.0f;
#pragma unroll
        for (int cl = 0; cl < 32; ++cl) {
            float t = S[cl * 256 + tid];
            sq = fmaf(t, t, sq);
        }
        hsqp[(size_t)(bm * 8 + w) * 256 + tid] = sq;
        float* htr = ht + ((size_t)(bm * 256 + tid)) * D + w * 32;
#pragma unroll
        for (int c4 = 0; c4 < 8; ++c4) {
            float4 t;
            t.x = S[(c4 * 4 + 0) * 256 + tid];
            t.y = S[(c4 * 4 + 1) * 256 + tid];
            t.z = S[(c4 * 4 + 2) * 256 + tid];
            t.w = S[(c4 * 4 + 3) * 256 + tid];
            *(float4*)(htr + c4 * 4) = t;
        }
        _Float16* dstT = Apk + (size_t)bm * 65536 + (size_t)w * 8192;
#pragma unroll
        for (int i = 0; i < 4; ++i) {  // q = i, r = tid
            alignas(16) _Float16 hi[8];
#pragma unroll
            for (int j = 0; j < 8; ++j) hi[j] = (_Float16)S[(i * 8 + j) * 256 + tid];
            *(half8*)(dstT + i * 2048 + tid * 8) = *(half8*)hi;
        }
    } else if (bid < 768) {
        const int bid2 = bid - 512;
        const int bn = bid2 >> 3, w = bid2 & 7;
        const int v0 = bn * 128;
#pragma unroll 4
        for (int i = 0; i < 16; ++i) {
            int flat = i * 256 + tid;
            int r = flat >> 5, cl = flat & 31;
            S[cl * 129 + r] = emb[(size_t)(v0 + r) * D + w * 32 + cl];
        }
        __syncthreads();
        _Float16* dstT = Bpk + (size_t)bn * 32768 + (size_t)w * 4096;
#pragma unroll
        for (int i = 0; i < 2; ++i) {
            int s = i * 256 + tid;
            int q = s >> 7, r = s & 127;
            alignas(16) _Float16 hi[8];
#pragma unroll
            for (int j = 0; j < 8; ++j) hi[j] = (_Float16)S[(q * 8 + j) * 129 + r];
            *(half8*)(dstT + q * 1024 + r * 8) = *(half8*)hi;
        }
    } else {
        __shared__ float sm[4];
        const int pid = bid - 768;  // 0..63
        const int lane = tid & 63, wv = tid >> 6;
        const int v0 = pid * 64;
        float lmax = 0.0f;
#pragma unroll 4
        for (int i = 0; i < 16; ++i) {
            int v = v0 + i * 4 + wv;
            float4 e = *(const float4*)(emb + (size_t)v * D + lane * 4);
            float s = e.x * e.x + e.y * e.y + e.z * e.z + e.w * e.w;
#pragma unroll
            for (int m = 32; m >= 1; m >>= 1) s += __shfl_xor(s, m, 64);
            if (lane == 0) esq[v] = s;
            lmax = fmaxf(lmax, s);
        }
        if (lane == 0) sm[wv] = lmax;
        __syncthreads();
        if (tid == 0) {
            e2maxp[pid] = fmaxf(fmaxf(sm[0], sm[1]), fmaxf(sm[2], sm[3]));
            if (pid == 0) out2[0] = 0.0f;
        }
    }
}

// ---------------- distance GEMM (LDS-free K-loop, round-10) + f32 embed top-2 ----------------
// K-loop = round 10 verbatim. Epilogue (the ONE change this round): per-(row,bn) top-2
// on bare f32 with the 7-bit within-block index embedded in the low mantissa
// (u = bits&~127 | code). Perturbation <= 127 ulp (~8e-3) absorbed by refine slack.
// Top-2-of-4 = v_min/v_max network; phase-B = 3 f32 ops; keys2 = float2 (4MB).
__global__ __launch_bounds__(256, 3) void k_gemm(const _Float16* __restrict__ Apk,
                                                 const _Float16* __restrict__ Bpk,
                                                 const float* __restrict__ esq,
                                                 float2* __restrict__ keys2) {
    __shared__ float2 t2[2048];  // [128 rows][16 j (xor row&7)] = 16KB

    const int tid = threadIdx.x;
    const int bid = blockIdx.x;
    const int swz = (bid & 7) * 512 + (bid >> 3);
    const int bm = swz >> 5, bn = swz & 31;
    const int m0 = bm * 128, n0 = bn * 128;

    const int wv = tid >> 6, l = tid & 63;
    const int wm = wv & 1, wn = wv >> 1;
    const int quad = l >> 4, j16 = l & 15;

    const _Float16* aP = Apk + (size_t)(bm >> 1) * 65536 + (size_t)(bm & 1) * 1024
                       + quad * 2048 + (wm * 64 + j16) * 8;
    const _Float16* bP = Bpk + (size_t)bn * 32768
                       + quad * 1024 + (wn * 64 + j16) * 8;

    f32x4 acc[4][4];
#pragma unroll
    for (int i = 0; i < 4; ++i)
#pragma unroll
        for (int j = 0; j < 4; ++j) acc[i][j] = (f32x4)0.0f;

    half8 af[4], bf[4], afn[4], bfn[4];
#pragma unroll
    for (int mt = 0; mt < 4; ++mt) af[mt] = *(const half8*)(aP + mt * 128);
#pragma unroll
    for (int nt = 0; nt < 4; ++nt) bf[nt] = *(const half8*)(bP + nt * 128);

#pragma unroll
    for (int w = 0; w < 8; ++w) {
        if (w < 7) {
#pragma unroll
            for (int mt = 0; mt < 4; ++mt)
                afn[mt] = *(const half8*)(aP + (w + 1) * 8192 + mt * 128);
#pragma unroll
            for (int nt = 0; nt < 4; ++nt)
                bfn[nt] = *(const half8*)(bP + (w + 1) * 4096 + nt * 128);
        }
        __builtin_amdgcn_s_setprio(1);
#pragma unroll
        for (int mt = 0; mt < 4; ++mt)
#pragma unroll
            for (int nt = 0; nt < 4; ++nt)
                acc[mt][nt] = __builtin_amdgcn_mfma_f32_16x16x32_f16(af[mt], bf[nt], acc[mt][nt], 0, 0, 0);
        __builtin_amdgcn_s_setprio(0);
#pragma unroll
        for (int mt = 0; mt < 4; ++mt) af[mt] = afn[mt];
#pragma unroll
        for (int nt = 0; nt < 4; ++nt) bf[nt] = bfn[nt];
    }

    // ---- epilogue: embedded-index f32 top-2 via LDS transpose ----
    float es[4];
    unsigned code[4];
#pragma unroll
    for (int nt = 0; nt < 4; ++nt) {
        code[nt] = (unsigned)(wn * 64 + nt * 16 + j16);   // v - bn*128, 7 bits
        es[nt] = esq[n0 + (int)code[nt]];
    }

    float M1 = __builtin_inff(), M2 = __builtin_inff();
#pragma unroll
    for (int pass = 0; pass < 2; ++pass) {
        if (wn == pass) {
#pragma unroll
            for (int mt = 0; mt < 4; ++mt) {
#pragma unroll
                for (int r = 0; r < 4; ++r) {
                    float c[4];
#pragma unroll
                    for (int nt = 0; nt < 4; ++nt) {
                        float dv = es[nt] - 2.0f * acc[mt][nt][r];
                        c[nt] = __uint_as_float((__float_as_uint(dv) & ~127u) | code[nt]);
                    }
                    float p = fminf(c[0], c[1]), q = fmaxf(c[0], c[1]);
                    float rr = fminf(c[2], c[3]), s = fmaxf(c[2], c[3]);
                    float m1 = fminf(p, rr);
                    float m2 = fminf(fmaxf(p, rr), fminf(q, s));
                    int row = wm * 64 + mt * 16 + quad * 4 + r;
                    t2[row * 16 + (j16 ^ (row & 7))] = make_float2(m1, m2);
                }
            }
        }
        __syncthreads();
        if (tid < 128) {
            const int row = tid;
#pragma unroll
            for (int j = 0; j < 16; ++j) {
                float2 a = t2[row * 16 + (j ^ (row & 7))];
                float t = fmaxf(M1, a.x);
                M1 = fminf(M1, a.x);
                M2 = fminf(fminf(M2, a.y), t);
            }
        }
        __syncthreads();
    }
    if (tid < 128)
        keys2[(size_t)(m0 + tid) * 32 + bn] = make_float2(M1, M2);
}

// ---------------- refine: windowed exact argmin -> out1 (READS out0-as-ht only) ----------------
// ROUND-10 structure (separate launch, exact_key_ht on ht, u64 exact keys); only the
// approx-key format changed to f32-embedded (fast-path decode from mantissa bits).
__device__ __forceinline__ u64 exact_key_ht(const float* __restrict__ ht,
                                            const float* __restrict__ emb,
                                            const float* __restrict__ esq,
                                            int rg, int v, int lane) {
    const float4 h4 = *(const float4*)(ht + (size_t)rg * D + lane * 4);
    const float4 e4 = *(const float4*)(emb + (size_t)v * D + lane * 4);
    float p = h4.x * e4.x;
    p = fmaf(h4.y, e4.y, p);
    p = fmaf(h4.z, e4.z, p);
    p = fmaf(h4.w, e4.w, p);
#pragma unroll
    for (int m = 32; m >= 1; m >>= 1) p += __shfl_xor(p, m, 64);
    return pack_key(esq[v] - 2.0f * p, v);
}

__global__ __launch_bounds__(256) void k_refine(const float* __restrict__ ht,  // = out0
                                                const float* __restrict__ emb,
                                                const float* __restrict__ esq,
                                                const float* __restrict__ hsqp,
                                                const float* __restrict__ e2maxp,
                                                const float* __restrict__ keys2f,
                                                float* __restrict__ out1) {
    __shared__ float sE2;
    const int tid = threadIdx.x;
    const int lane = tid & 63;
    const int w = tid >> 6;
    const int n0 = blockIdx.x * 32;

    if (tid < 64) {
        float m = e2maxp[tid];
#pragma unroll
        for (int s = 32; s >= 1; s >>= 1) m = fmaxf(m, __shfl_xor(m, s, 64));
        if (tid == 0) sE2 = m;
    }
    __syncthreads();
    const float e2m = sE2;

    // wave w owns rows w*8 .. w*8+7; prefetch next row's keys under current reduce
    int rg = n0 + w * 8;
    float key = keys2f[(size_t)rg * 64 + lane];
#pragma unroll 1
    for (int rr = 0; rr < 8; ++rr, ++rg) {
        float keyn = 0.0f;
        if (rr < 7) keyn = keys2f[(size_t)(rg + 1) * 64 + lane];
        float gm = key;
#pragma unroll
        for (int m = 32; m >= 1; m >>= 1) gm = fminf(gm, __shfl_xor(gm, m, 64));
        // sound window: |approx - true| <= B (f16) + ~8e-3 (embed); thr = gm+2B+slack
        float hq = 0.0f;
#pragma unroll
        for (int k = 0; k < 8; ++k) hq += hsqp[(size_t)(rg >> 8) * 2048 + k * 256 + (rg & 255)];
        const float thr = gm + 4.0e-3f * sqrtf(hq * e2m) + 5.0e-2f;
        u64 cmask = __ballot(key <= thr);
        int bidx;
        if (__popcll(cmask) == 1) {
            // fast path: only gmin in-window; every block's unstored (rank>=3) keys
            // >= its slot-2 > thr => gmin's embedded index is the exact argmin.
            // (duplicate keys across blocks would both be <= thr => popc>=2.)
            u64 own = __ballot(key == gm);
            int L = __ffsll((long long)own) - 1;
            bidx = (L >> 1) * 128 + (int)(__float_as_uint(gm) & 127u);
        } else {
            u64 bestk = ~0ULL;
            u64 rescan = 0;
            u64 cm = cmask;
            while (cm) {
                int L = __ffsll((long long)cm) - 1;
                cm &= cm - 1;
                if (L & 1) {
                    rescan |= 1ull << (L >> 1);
                } else {
                    float kL = __shfl(key, L, 64);
                    int v = (L >> 1) * 128 + (int)(__float_as_uint(kL) & 127u);
                    u64 ek = exact_key_ht(ht, emb, esq, rg, v, lane);
                    bestk = ek < bestk ? ek : bestk;
                }
            }
            // rare path, LANE-PARALLEL: 64 lanes x 2 candidates, serial f32 dot
            // (ht row broadcast, emb from L2), top-2 wave reduce, exact re-eval of
            // the 2 survivors (shared exact rounding). Proven in rounds 7-10.
            while (rescan) {
                int bnr = __ffsll((long long)rescan) - 1;
                rescan &= rescan - 1;
                const float* htr = ht + (size_t)rg * D;
                u64 k0 = ~0ULL, k1 = ~0ULL;
#pragma unroll
                for (int c = 0; c < 2; ++c) {
                    int v = bnr * 128 + c * 64 + lane;
                    float p = 0.0f;
#pragma unroll 8
                    for (int d = 0; d < D; d += 4) {
                        float4 hh = *(const float4*)(htr + d);
                        float4 ee = *(const float4*)(emb + (size_t)v * D + d);
                        p = fmaf(hh.x, ee.x, p);
                        p = fmaf(hh.y, ee.y, p);
                        p = fmaf(hh.z, ee.z, p);
                        p = fmaf(hh.w, ee.w, p);
                    }
                    u64 kc = pack_key(esq[v] - 2.0f * p, v);
                    if (c == 0) k0 = kc; else k1 = kc;
                }
                u64 m1 = k0 < k1 ? k0 : k1, m2 = k0 < k1 ? k1 : k0;
#pragma unroll
                for (int m = 32; m >= 1; m >>= 1) {
                    u64 o1 = __shfl_xor(m1, m, 64), o2 = __shfl_xor(m2, m, 64);
                    u64 hi = m1 > o1 ? m1 : o1;
                    m1 = m1 < o1 ? m1 : o1;
                    u64 lo2 = m2 < o2 ? m2 : o2;
                    m2 = hi < lo2 ? hi : lo2;
                }
                u64 e1 = exact_key_ht(ht, emb, esq, rg, (int)(m1 & 0xFFFFFFFFu), lane);
                u64 e2 = exact_key_ht(ht, emb, esq, rg, (int)(m2 & 0xFFFFFFFFu), lane);
                bestk = e1 < bestk ? e1 : bestk;
                bestk = e2 < bestk ? e2 : bestk;
            }
            bidx = (int)(bestk & 0xFFFFFFFFu);
        }
        if (lane == 0) out1[rg] = (float)bidx;
        key = keyn;
    }
}

// ---------------- out: gather emb by index, write z_q_st (overwrites ht) + loss ----------------
// ROUND-10 VERBATIM. Separate launch AFTER k_refine: kernel boundary guarantees every
// block's ht reads finished before any out0 overwrite.
__global__ __launch_bounds__(256) void k_out(const float* __restrict__ h,
                                             const float* __restrict__ emb,
                                             const float* __restrict__ out1,
                                             float* __restrict__ out0,
                                             float* __restrict__ out2) {
    __shared__ float zq[32][260];
    __shared__ float wred[4];
    const int tid = threadIdx.x;
    const int lane = tid & 63;
    const int w = tid >> 6;
    const int n0 = blockIdx.x * 32;
    const int b = n0 >> 10;
    const int p0 = n0 & 1023;
#pragma unroll
    for (int rr = 0; rr < 8; ++rr) {
        int r = w * 8 + rr;
        unsigned idx = (unsigned)(int)out1[n0 + r];
        float4 e4 = *(const float4*)(emb + (size_t)idx * D + lane * 4);
        *(float4*)&zq[r][lane * 4] = e4;
    }
    __syncthreads();
    float lsum = 0.0f;
    const size_t base = ((size_t)b * D) << 10;
#pragma unroll 4
    for (int it = 0; it < 32; ++it) {
        int c = it * 8 + (tid >> 5);
        int pp = tid & 31;
        float z = zq[pp][c];
        size_t g = base + ((size_t)c << 10) + p0 + pp;
        float hv = h[g];
        out0[g] = hv + (z - hv);
        float d = hv - z;
        lsum = fmaf(d, d, lsum);
    }
#pragma unroll
    for (int m = 32; m >= 1; m >>= 1) lsum += __shfl_xor(lsum, m, 64);
    if (lane == 0) wred[w] = lsum;
    __syncthreads();
    if (tid == 0)
        atomicAdd(out2, (wred[0] + wred[1] + wred[2] + wred[3]) * (1.0f / (float)N_OUT0));
}

extern "C" void kernel_launch(void* const* d_in, const int* in_sizes, int n_in,
                              void* d_out, int out_size, void* d_ws, size_t ws_size,
                              hipStream_t stream) {
    const float* h = (const float*)d_in[0];
    const float* emb = (const float*)d_in[1];
    float* out0 = (float*)d_out;
    float* out1 = out0 + N_OUT0;
    float* out2 = out1 + NTOT;

    // ws: Apk 8MB | Bpk 2MB | esq 16KB | hsqp 512KB | e2maxp 1KB | keys2f 4MB (~14.5MB)
    // ht (16MB) lives in out0 until k_out (round-10 proven lifetime).
    char* wsb = (char*)d_ws;
    _Float16* Apk = (_Float16*)wsb;
    _Float16* Bpk = (_Float16*)(wsb + 8388608);
    float* esq = (float*)(wsb + 10485760);
    float* hsqp = (float*)(wsb + 10502144);
    float* e2maxp = (float*)(wsb + 11026432);
    float* keys2f = (float*)(wsb + 11028480);

    hipLaunchKernelGGL(k_pack, dim3(832), dim3(256), 0, stream, h, emb, Apk, Bpk, hsqp, out0, esq, e2maxp, out2);
    hipLaunchKernelGGL(k_gemm, dim3(4096), dim3(256), 0, stream, Apk, Bpk, esq, (float2*)keys2f);
    hipLaunchKernelGGL(k_refine, dim3(NTOT / 32), dim3(256), 0, stream, out0, emb, esq, hsqp, e2maxp, keys2f, out1);
    hipLaunchKernelGGL(k_out, dim3(NTOT / 32), dim3(256), 0, stream, h, emb, out1, out0, out2);
}

// Round 13
// 169.232 us; speedup vs baseline: 1.8111x; 1.0060x over previous
//
#include <hip/hip_runtime.h>

#define D 256
#define VOCAB 4096
#define NTOT 16384      // 16 * 32 * 32
#define N_OUT0 4194304  // 16*256*32*32

typedef _Float16 half8 __attribute__((ext_vector_type(8)));
typedef float f32x4 __attribute__((ext_vector_type(4)));
typedef unsigned long long u64;

__device__ __forceinline__ u64 pack_key(float d, int v) {
    unsigned u = __float_as_uint(d);
    u ^= ((unsigned)((int)u >> 31)) | 0x80000000u;  // monotonic float->uint
    return ((u64)u << 32) | (unsigned)v;
}

// ---------------- fused pack (hi-only) + hsq + ht + esq/e2max prep ----------------
// blocks 0..511: pack A (hi) + hsq partials + ht (BLOCKED layout, stored IN out0 —
//   dead until k_out overwrites it; k_refine only READS it, k_out runs after);
// 512..767: pack B (hi); 768..831: esq + e2maxp partials (+ out2 zero at 768)
// ht blocked layout (round 13): htb[s=bm*8+w][r=0..255][c=0..31] holding
//   h_flat[bm*256+r][w*32+c]. Write side: a wave fills one dense contiguous 8KB
//   region (64 rows x 128B) — fully coalesced, vs the old row-major pattern of
//   64 x 16B partial lines at 1KB stride (write-combine thrash, ~2-4x HBM cost).
__global__ __launch_bounds__(256) void k_pack(const float* __restrict__ h,
                                              const float* __restrict__ emb,
                                              _Float16* __restrict__ Apk,
                                              _Float16* __restrict__ Bpk,
                                              float* __restrict__ hsqp,
                                              float* __restrict__ ht,
                                              float* __restrict__ esq,
                                              float* __restrict__ e2maxp,
                                              float* __restrict__ out2) {
    __shared__ float S[8192];
    const int tid = threadIdx.x;
    const int bid = blockIdx.x;
    if (bid < 512) {
        const int bm = bid >> 3, w = bid & 7;
        const int b = bm >> 2, p0 = (bm & 3) * 256;
        const float* src = h + ((size_t)b << 18) + p0;
#pragma unroll 4
        for (int cl = 0; cl < 32; ++cl)
            S[cl * 256 + tid] = src[(size_t)(w * 32 + cl) << 10 | (unsigned)tid];
        __syncthreads();
        float sq = 0.0f;
#pragma unroll
        for (int cl = 0; cl < 32; ++cl) {
            float t = S[cl * 256 + tid];
            sq = fmaf(t, t, sq);
        }
        hsqp[(size_t)(bm * 8 + w) * 256 + tid] = sq;
        // ht blocked: htb[(bm*8+w)*256 + tid][0..31]  (contiguous 128B per thread)
        float* htr = ht + ((size_t)((bm * 8 + w) * 256 + tid)) * 32;
#pragma unroll
        for (int c4 = 0; c4 < 8; ++c4) {
            float4 t;
            t.x = S[(c4 * 4 + 0) * 256 + tid];
            t.y = S[(c4 * 4 + 1) * 256 + tid];
            t.z = S[(c4 * 4 + 2) * 256 + tid];
            t.w = S[(c4 * 4 + 3) * 256 + tid];
            *(float4*)(htr + c4 * 4) = t;
        }
        _Float16* dstT = Apk + (size_t)bm * 65536 + (size_t)w * 8192;
#pragma unroll
        for (int i = 0; i < 4; ++i) {  // q = i, r = tid
            alignas(16) _Float16 hi[8];
#pragma unroll
            for (int j = 0; j < 8; ++j) hi[j] = (_Float16)S[(i * 8 + j) * 256 + tid];
            *(half8*)(dstT + i * 2048 + tid * 8) = *(half8*)hi;
        }
    } else if (bid < 768) {
        const int bid2 = bid - 512;
        const int bn = bid2 >> 3, w = bid2 & 7;
        const int v0 = bn * 128;
#pragma unroll 4
        for (int i = 0; i < 16; ++i) {
            int flat = i * 256 + tid;
            int r = flat >> 5, cl = flat & 31;
            S[cl * 129 + r] = emb[(size_t)(v0 + r) * D + w * 32 + cl];
        }
        __syncthreads();
        _Float16* dstT = Bpk + (size_t)bn * 32768 + (size_t)w * 4096;
#pragma unroll
        for (int i = 0; i < 2; ++i) {
            int s = i * 256 + tid;
            int q = s >> 7, r = s & 127;
            alignas(16) _Float16 hi[8];
#pragma unroll
            for (int j = 0; j < 8; ++j) hi[j] = (_Float16)S[(q * 8 + j) * 129 + r];
            *(half8*)(dstT + q * 1024 + r * 8) = *(half8*)hi;
        }
    } else {
        __shared__ float sm[4];
        const int pid = bid - 768;  // 0..63
        const int lane = tid & 63, wv = tid >> 6;
        const int v0 = pid * 64;
        float lmax = 0.0f;
#pragma unroll 4
        for (int i = 0; i < 16; ++i) {
            int v = v0 + i * 4 + wv;
            float4 e = *(const float4*)(emb + (size_t)v * D + lane * 4);
            float s = e.x * e.x + e.y * e.y + e.z * e.z + e.w * e.w;
#pragma unroll
            for (int m = 32; m >= 1; m >>= 1) s += __shfl_xor(s, m, 64);
            if (lane == 0) esq[v] = s;
            lmax = fmaxf(lmax, s);
        }
        if (lane == 0) sm[wv] = lmax;
        __syncthreads();
        if (tid == 0) {
            e2maxp[pid] = fmaxf(fmaxf(sm[0], sm[1]), fmaxf(sm[2], sm[3]));
            if (pid == 0) out2[0] = 0.0f;
        }
    }
}

// ---------------- distance GEMM (LDS-free K-loop) + f32 embed top-2 ----------------
// ROUND-12 VERBATIM (proven). Per-(row,bn) top-2 on bare f32 with the 7-bit
// within-block index embedded in the low mantissa; perturbation <= 127 ulp absorbed
// by refine slack. keys2 = float2 (4MB).
__global__ __launch_bounds__(256, 3) void k_gemm(const _Float16* __restrict__ Apk,
                                                 const _Float16* __restrict__ Bpk,
                                                 const float* __restrict__ esq,
                                                 float2* __restrict__ keys2) {
    __shared__ float2 t2[2048];  // [128 rows][16 j (xor row&7)] = 16KB

    const int tid = threadIdx.x;
    const int bid = blockIdx.x;
    const int swz = (bid & 7) * 512 + (bid >> 3);
    const int bm = swz >> 5, bn = swz & 31;
    const int m0 = bm * 128, n0 = bn * 128;

    const int wv = tid >> 6, l = tid & 63;
    const int wm = wv & 1, wn = wv >> 1;
    const int quad = l >> 4, j16 = l & 15;

    const _Float16* aP = Apk + (size_t)(bm >> 1) * 65536 + (size_t)(bm & 1) * 1024
                       + quad * 2048 + (wm * 64 + j16) * 8;
    const _Float16* bP = Bpk + (size_t)bn * 32768
                       + quad * 1024 + (wn * 64 + j16) * 8;

    f32x4 acc[4][4];
#pragma unroll
    for (int i = 0; i < 4; ++i)
#pragma unroll
        for (int j = 0; j < 4; ++j) acc[i][j] = (f32x4)0.0f;

    half8 af[4], bf[4], afn[4], bfn[4];
#pragma unroll
    for (int mt = 0; mt < 4; ++mt) af[mt] = *(const half8*)(aP + mt * 128);
#pragma unroll
    for (int nt = 0; nt < 4; ++nt) bf[nt] = *(const half8*)(bP + nt * 128);

#pragma unroll
    for (int w = 0; w < 8; ++w) {
        if (w < 7) {
#pragma unroll
            for (int mt = 0; mt < 4; ++mt)
                afn[mt] = *(const half8*)(aP + (w + 1) * 8192 + mt * 128);
#pragma unroll
            for (int nt = 0; nt < 4; ++nt)
                bfn[nt] = *(const half8*)(bP + (w + 1) * 4096 + nt * 128);
        }
        __builtin_amdgcn_s_setprio(1);
#pragma unroll
        for (int mt = 0; mt < 4; ++mt)
#pragma unroll
            for (int nt = 0; nt < 4; ++nt)
                acc[mt][nt] = __builtin_amdgcn_mfma_f32_16x16x32_f16(af[mt], bf[nt], acc[mt][nt], 0, 0, 0);
        __builtin_amdgcn_s_setprio(0);
#pragma unroll
        for (int mt = 0; mt < 4; ++mt) af[mt] = afn[mt];
#pragma unroll
        for (int nt = 0; nt < 4; ++nt) bf[nt] = bfn[nt];
    }

    // ---- epilogue: embedded-index f32 top-2 via LDS transpose ----
    float es[4];
    unsigned code[4];
#pragma unroll
    for (int nt = 0; nt < 4; ++nt) {
        code[nt] = (unsigned)(wn * 64 + nt * 16 + j16);   // v - bn*128, 7 bits
        es[nt] = esq[n0 + (int)code[nt]];
    }

    float M1 = __builtin_inff(), M2 = __builtin_inff();
#pragma unroll
    for (int pass = 0; pass < 2; ++pass) {
        if (wn == pass) {
#pragma unroll
            for (int mt = 0; mt < 4; ++mt) {
#pragma unroll
                for (int r = 0; r < 4; ++r) {
                    float c[4];
#pragma unroll
                    for (int nt = 0; nt < 4; ++nt) {
                        float dv = es[nt] - 2.0f * acc[mt][nt][r];
                        c[nt] = __uint_as_float((__float_as_uint(dv) & ~127u) | code[nt]);
                    }
                    float p = fminf(c[0], c[1]), q = fmaxf(c[0], c[1]);
                    float rr = fminf(c[2], c[3]), s = fmaxf(c[2], c[3]);
                    float m1 = fminf(p, rr);
                    float m2 = fminf(fmaxf(p, rr), fminf(q, s));
                    int row = wm * 64 + mt * 16 + quad * 4 + r;
                    t2[row * 16 + (j16 ^ (row & 7))] = make_float2(m1, m2);
                }
            }
        }
        __syncthreads();
        if (tid < 128) {
            const int row = tid;
#pragma unroll
            for (int j = 0; j < 16; ++j) {
                float2 a = t2[row * 16 + (j ^ (row & 7))];
                float t = fmaxf(M1, a.x);
                M1 = fminf(M1, a.x);
                M2 = fminf(fminf(M2, a.y), t);
            }
        }
        __syncthreads();
    }
    if (tid < 128)
        keys2[(size_t)(m0 + tid) * 32 + bn] = make_float2(M1, M2);
}

// ---------------- refine: windowed exact argmin -> out1 (READS out0-as-ht only) ----------------
// ROUND-12 logic; only the ht addressing changed to the blocked layout:
//   h_flat[rg][ch] at htb[(rg>>8)*65536 + (ch>>5)*8192 + (rg&255)*32 + (ch&31)]
__device__ __forceinline__ u64 exact_key_ht(const float* __restrict__ htb,
                                            const float* __restrict__ emb,
                                            const float* __restrict__ esq,
                                            int rg, int v, int lane) {
    const float4 h4 = *(const float4*)(htb + (((size_t)(rg >> 8)) << 16)
                                           + ((size_t)(lane >> 3) << 13)
                                           + ((rg & 255) << 5) + ((lane & 7) << 2));
    const float4 e4 = *(const float4*)(emb + (size_t)v * D + lane * 4);
    float p = h4.x * e4.x;
    p = fmaf(h4.y, e4.y, p);
    p = fmaf(h4.z, e4.z, p);
    p = fmaf(h4.w, e4.w, p);
#pragma unroll
    for (int m = 32; m >= 1; m >>= 1) p += __shfl_xor(p, m, 64);
    return pack_key(esq[v] - 2.0f * p, v);
}

__global__ __launch_bounds__(256) void k_refine(const float* __restrict__ ht,  // = out0 (blocked)
                                                const float* __restrict__ emb,
                                                const float* __restrict__ esq,
                                                const float* __restrict__ hsqp,
                                                const float* __restrict__ e2maxp,
                                                const float* __restrict__ keys2f,
                                                float* __restrict__ out1) {
    __shared__ float sE2;
    const int tid = threadIdx.x;
    const int lane = tid & 63;
    const int w = tid >> 6;
    const int n0 = blockIdx.x * 32;

    if (tid < 64) {
        float m = e2maxp[tid];
#pragma unroll
        for (int s = 32; s >= 1; s >>= 1) m = fmaxf(m, __shfl_xor(m, s, 64));
        if (tid == 0) sE2 = m;
    }
    __syncthreads();
    const float e2m = sE2;

    // wave w owns rows w*8 .. w*8+7; prefetch next row's keys under current reduce
    int rg = n0 + w * 8;
    float key = keys2f[(size_t)rg * 64 + lane];
#pragma unroll 1
    for (int rr = 0; rr < 8; ++rr, ++rg) {
        float keyn = 0.0f;
        if (rr < 7) keyn = keys2f[(size_t)(rg + 1) * 64 + lane];
        float gm = key;
#pragma unroll
        for (int m = 32; m >= 1; m >>= 1) gm = fminf(gm, __shfl_xor(gm, m, 64));
        // sound window: |approx - true| <= B (f16) + ~8e-3 (embed); thr = gm+2B+slack
        float hq = 0.0f;
#pragma unroll
        for (int k = 0; k < 8; ++k) hq += hsqp[(size_t)(rg >> 8) * 2048 + k * 256 + (rg & 255)];
        const float thr = gm + 4.0e-3f * sqrtf(hq * e2m) + 5.0e-2f;
        u64 cmask = __ballot(key <= thr);
        int bidx;
        if (__popcll(cmask) == 1) {
            // fast path: only gmin in-window; every block's unstored (rank>=3) keys
            // >= its slot-2 > thr => gmin's embedded index is the exact argmin.
            u64 own = __ballot(key == gm);
            int L = __ffsll((long long)own) - 1;
            bidx = (L >> 1) * 128 + (int)(__float_as_uint(gm) & 127u);
        } else {
            u64 bestk = ~0ULL;
            u64 rescan = 0;
            u64 cm = cmask;
            while (cm) {
                int L = __ffsll((long long)cm) - 1;
                cm &= cm - 1;
                if (L & 1) {
                    rescan |= 1ull << (L >> 1);
                } else {
                    float kL = __shfl(key, L, 64);
                    int v = (L >> 1) * 128 + (int)(__float_as_uint(kL) & 127u);
                    u64 ek = exact_key_ht(ht, emb, esq, rg, v, lane);
                    bestk = ek < bestk ? ek : bestk;
                }
            }
            // rare path, LANE-PARALLEL: 64 lanes x 2 candidates, serial f32 dot
            // (ht row broadcast, emb from L2), top-2 wave reduce, exact re-eval of
            // the 2 survivors (shared exact rounding).
            while (rescan) {
                int bnr = __ffsll((long long)rescan) - 1;
                rescan &= rescan - 1;
                const float* htr = ht + (((size_t)(rg >> 8)) << 16) + ((rg & 255) << 5);
                u64 k0 = ~0ULL, k1 = ~0ULL;
#pragma unroll
                for (int c = 0; c < 2; ++c) {
                    int v = bnr * 128 + c * 64 + lane;
                    float p = 0.0f;
#pragma unroll 8
                    for (int d = 0; d < D; d += 4) {
                        float4 hh = *(const float4*)(htr + ((d >> 5) << 13) + (d & 31));
                        float4 ee = *(const float4*)(emb + (size_t)v * D + d);
                        p = fmaf(hh.x, ee.x, p);
                        p = fmaf(hh.y, ee.y, p);
                        p = fmaf(hh.z, ee.z, p);
                        p = fmaf(hh.w, ee.w, p);
                    }
                    u64 kc = pack_key(esq[v] - 2.0f * p, v);
                    if (c == 0) k0 = kc; else k1 = kc;
                }
                u64 m1 = k0 < k1 ? k0 : k1, m2 = k0 < k1 ? k1 : k0;
#pragma unroll
                for (int m = 32; m >= 1; m >>= 1) {
                    u64 o1 = __shfl_xor(m1, m, 64), o2 = __shfl_xor(m2, m, 64);
                    u64 hi = m1 > o1 ? m1 : o1;
                    m1 = m1 < o1 ? m1 : o1;
                    u64 lo2 = m2 < o2 ? m2 : o2;
                    m2 = hi < lo2 ? hi : lo2;
                }
                u64 e1 = exact_key_ht(ht, emb, esq, rg, (int)(m1 & 0xFFFFFFFFu), lane);
                u64 e2 = exact_key_ht(ht, emb, esq, rg, (int)(m2 & 0xFFFFFFFFu), lane);
                bestk = e1 < bestk ? e1 : bestk;
                bestk = e2 < bestk ? e2 : bestk;
            }
            bidx = (int)(bestk & 0xFFFFFFFFu);
        }
        if (lane == 0) out1[rg] = (float)bidx;
        key = keyn;
    }
}

// ---------------- out: gather emb by index, write z_q_st (overwrites ht) + loss ----------------
// ROUND-12 VERBATIM. Separate launch AFTER k_refine: kernel boundary guarantees every
// block's ht reads finished before any out0 overwrite.
__global__ __launch_bounds__(256) void k_out(const float* __restrict__ h,
                                             const float* __restrict__ emb,
                                             const float* __restrict__ out1,
                                             float* __restrict__ out0,
                                             float* __restrict__ out2) {
    __shared__ float zq[32][260];
    __shared__ float wred[4];
    const int tid = threadIdx.x;
    const int lane = tid & 63;
    const int w = tid >> 6;
    const int n0 = blockIdx.x * 32;
    const int b = n0 >> 10;
    const int p0 = n0 & 1023;
#pragma unroll
    for (int rr = 0; rr < 8; ++rr) {
        int r = w * 8 + rr;
        unsigned idx = (unsigned)(int)out1[n0 + r];
        float4 e4 = *(const float4*)(emb + (size_t)idx * D + lane * 4);
        *(float4*)&zq[r][lane * 4] = e4;
    }
    __syncthreads();
    float lsum = 0.0f;
    const size_t base = ((size_t)b * D) << 10;
#pragma unroll 4
    for (int it = 0; it < 32; ++it) {
        int c = it * 8 + (tid >> 5);
        int pp = tid & 31;
        float z = zq[pp][c];
        size_t g = base + ((size_t)c << 10) + p0 + pp;
        float hv = h[g];
        out0[g] = hv + (z - hv);
        float d = hv - z;
        lsum = fmaf(d, d, lsum);
    }
#pragma unroll
    for (int m = 32; m >= 1; m >>= 1) lsum += __shfl_xor(lsum, m, 64);
    if (lane == 0) wred[w] = lsum;
    __syncthreads();
    if (tid == 0)
        atomicAdd(out2, (wred[0] + wred[1] + wred[2] + wred[3]) * (1.0f / (float)N_OUT0));
}

extern "C" void kernel_launch(void* const* d_in, const int* in_sizes, int n_in,
                              void* d_out, int out_size, void* d_ws, size_t ws_size,
                              hipStream_t stream) {
    const float* h = (const float*)d_in[0];
    const float* emb = (const float*)d_in[1];
    float* out0 = (float*)d_out;
    float* out1 = out0 + N_OUT0;
    float* out2 = out1 + NTOT;

    // ws: Apk 8MB | Bpk 2MB | esq 16KB | hsqp 512KB | e2maxp 1KB | keys2f 4MB (~14.5MB)
    // ht (16MB, BLOCKED layout) lives in out0 until k_out (proven lifetime).
    char* wsb = (char*)d_ws;
    _Float16* Apk = (_Float16*)wsb;
    _Float16* Bpk = (_Float16*)(wsb + 8388608);
    float* esq = (float*)(wsb + 10485760);
    float* hsqp = (float*)(wsb + 10502144);
    float* e2maxp = (float*)(wsb + 11026432);
    float* keys2f = (float*)(wsb + 11028480);

    hipLaunchKernelGGL(k_pack, dim3(832), dim3(256), 0, stream, h, emb, Apk, Bpk, hsqp, out0, esq, e2maxp, out2);
    hipLaunchKernelGGL(k_gemm, dim3(4096), dim3(256), 0, stream, Apk, Bpk, esq, (float2*)keys2f);
    hipLaunchKernelGGL(k_refine, dim3(NTOT / 32), dim3(256), 0, stream, out0, emb, esq, hsqp, e2maxp, keys2f, out1);
    hipLaunchKernelGGL(k_out, dim3(NTOT / 32), dim3(256), 0, stream, h, emb, out1, out0, out2);
}